// Round 1
// baseline (1078.738 us; speedup 1.0000x reference)
//
#include <hip/hip_runtime.h>

#define Nn 50000
#define Ee 800000
#define INF_ 256
#define HID 128
#define NC 40
#define CAP 64
#define LPA_ITERS 10

// ---------------------------------------------------------------------------
// Mask format detection: mask may arrive as int32 {0,1} or as packed bytes
// {0,1}. Read first 12500 u32 words (covers both layouts in-bounds); any
// word >1 means byte-packed.
__global__ void detect_fmt(const unsigned int* __restrict__ m, int* flag) {
    int i = blockIdx.x * blockDim.x + threadIdx.x;
    if (i < 12500) {
        if (m[i] > 1u) atomicOr(flag, 1);
    }
}

__device__ inline bool read_mask(const void* mask, int node, int fmt) {
    if (fmt) return ((const unsigned char*)mask)[node] != 0;
    return ((const int*)mask)[node] != 0;
}

// ---------------------------------------------------------------------------
// Build fixed-capacity adjacency lists (both directions). cnt_* double as
// degree arrays afterwards.
__global__ void fill_csr(const int* __restrict__ src, const int* __restrict__ dst,
                         int* cnt_src, int* cnt_dst,
                         int* __restrict__ adj_src, int* __restrict__ adj_dst) {
    int e = blockIdx.x * blockDim.x + threadIdx.x;
    if (e < Ee) {
        int s = src[e], d = dst[e];
        int ps = atomicAdd(&cnt_src[s], 1);
        if (ps < CAP) adj_src[s * CAP + ps] = d;
        int pd = atomicAdd(&cnt_dst[d], 1);
        if (pd < CAP) adj_dst[d * CAP + pd] = s;
    }
}

// ---------------------------------------------------------------------------
// GEMM1: h1[n, j] = (sum_k feat[n,k] * W1[k,j]) * norm_src[n]
// 64 rows x 128 cols per block of 256 threads; K-tiles of 32.
#define G1_ROWS 64
#define G1_KT 32
__global__ __launch_bounds__(256) void gemm1(
    const float* __restrict__ feat, const float* __restrict__ W1,
    const int* __restrict__ cnt_src, float* __restrict__ h1) {
    __shared__ float lA[G1_ROWS][G1_KT + 1];  // [row][k], +1 pad
    __shared__ float lB[G1_KT][HID];          // [k][col]
    const int tid = threadIdx.x;
    const int row0 = blockIdx.x * G1_ROWS;
    const int r0 = (tid >> 4) * 4;   // 0..60
    const int c0 = (tid & 15) * 8;   // 0..120

    float acc[4][8];
#pragma unroll
    for (int i = 0; i < 4; i++)
#pragma unroll
        for (int j = 0; j < 8; j++) acc[i][j] = 0.f;

    for (int k0 = 0; k0 < INF_; k0 += G1_KT) {
        // stage A tile: 64 rows x 32 k = 512 float4, 2 per thread
#pragma unroll
        for (int p = 0; p < 2; p++) {
            int idx = tid + p * 256;
            int r = idx >> 3, c4 = idx & 7;
            int grow = row0 + r;
            float4 v = make_float4(0.f, 0.f, 0.f, 0.f);
            if (grow < Nn)
                v = *(const float4*)(feat + (size_t)grow * INF_ + k0 + c4 * 4);
            lA[r][c4 * 4 + 0] = v.x;
            lA[r][c4 * 4 + 1] = v.y;
            lA[r][c4 * 4 + 2] = v.z;
            lA[r][c4 * 4 + 3] = v.w;
        }
        // stage B tile: 32 k x 128 cols = 1024 float4, 4 per thread
#pragma unroll
        for (int p = 0; p < 4; p++) {
            int idx = tid + p * 256;
            int kb = idx >> 5, c4 = idx & 31;
            *(float4*)(&lB[kb][c4 * 4]) =
                *(const float4*)(W1 + (size_t)(k0 + kb) * HID + c4 * 4);
        }
        __syncthreads();
#pragma unroll 8
        for (int k = 0; k < G1_KT; k++) {
            float a[4];
#pragma unroll
            for (int i = 0; i < 4; i++) a[i] = lA[r0 + i][k];
            float4 bv0 = *(const float4*)(&lB[k][c0]);
            float4 bv1 = *(const float4*)(&lB[k][c0 + 4]);
            float b[8] = {bv0.x, bv0.y, bv0.z, bv0.w, bv1.x, bv1.y, bv1.z, bv1.w};
#pragma unroll
            for (int i = 0; i < 4; i++)
#pragma unroll
                for (int j = 0; j < 8; j++) acc[i][j] += a[i] * b[j];
        }
        __syncthreads();
    }
#pragma unroll
    for (int i = 0; i < 4; i++) {
        int grow = row0 + r0 + i;
        if (grow < Nn) {
            int dg = cnt_src[grow];
            float nrm = rsqrtf((float)(dg > 1 ? dg : 1));
            float* op = h1 + (size_t)grow * HID + c0;
#pragma unroll
            for (int j = 0; j < 8; j++) op[j] = acc[i][j] * nrm;
        }
    }
}

// ---------------------------------------------------------------------------
// agg1: x1[i,:] = relu( norm_dst[i] * sum_{e: dst=i} h1[src_e,:] + b1 )
// block 256 = 2 nodes x 128 cols
__global__ __launch_bounds__(256) void agg_relu1(
    const float* __restrict__ h1, const int* __restrict__ adj_dst,
    const int* __restrict__ cnt_dst, const float* __restrict__ b1,
    float* __restrict__ x1) {
    int node = blockIdx.x * 2 + (threadIdx.x >> 7);
    int j = threadIdx.x & 127;
    if (node >= Nn) return;
    int dg = cnt_dst[node];
    int cnt = dg < CAP ? dg : CAP;
    const int* lst = adj_dst + (size_t)node * CAP;
    float sum = 0.f;
    for (int e = 0; e < cnt; e++) {
        int s = lst[e];
        sum += h1[(size_t)s * HID + j];
    }
    float nrm = rsqrtf((float)(dg > 1 ? dg : 1));
    float v = sum * nrm + b1[j];
    x1[(size_t)node * HID + j] = v > 0.f ? v : 0.f;
}

// ---------------------------------------------------------------------------
// GEMM2: h2[n,c] = (sum_k x1[n,k] * W2[k,c]) * norm_src[n]
// block 320 threads: 8 row-groups x 40 cols, 4 rows per thread
__global__ __launch_bounds__(320) void gemm2(
    const float* __restrict__ x1, const float* __restrict__ W2,
    const int* __restrict__ cnt_src, float* __restrict__ h2) {
    int tid = threadIdx.x;
    int c = tid % NC;
    int rg = tid / NC;  // 0..7
    int row0 = blockIdx.x * 32 + rg * 4;
    int rc[4];
#pragma unroll
    for (int i = 0; i < 4; i++) {
        int r = row0 + i;
        rc[i] = r < Nn ? r : Nn - 1;
    }
    float acc[4] = {0.f, 0.f, 0.f, 0.f};
    for (int k = 0; k < HID; k++) {
        float w = W2[(size_t)k * NC + c];
#pragma unroll
        for (int i = 0; i < 4; i++) acc[i] += x1[(size_t)rc[i] * HID + k] * w;
    }
#pragma unroll
    for (int i = 0; i < 4; i++) {
        int r = row0 + i;
        if (r < Nn) {
            int dg = cnt_src[r];
            float nrm = rsqrtf((float)(dg > 1 ? dg : 1));
            h2[(size_t)r * NC + c] = acc[i] * nrm;
        }
    }
}

// ---------------------------------------------------------------------------
// agg2: out_x[i,c] = norm_dst[i] * sum_{e: dst=i} h2[src_e,c] + b2[c]
// block 320 = 8 nodes x 40 cols
__global__ __launch_bounds__(320) void agg2(
    const float* __restrict__ h2, const int* __restrict__ adj_dst,
    const int* __restrict__ cnt_dst, const float* __restrict__ b2,
    float* __restrict__ out_x) {
    int tid = threadIdx.x;
    int node = blockIdx.x * 8 + tid / NC;
    int c = tid % NC;
    int dg = cnt_dst[node];
    int cnt = dg < CAP ? dg : CAP;
    const int* lst = adj_dst + (size_t)node * CAP;
    float sum = 0.f;
    for (int e = 0; e < cnt; e++) sum += h2[(size_t)lst[e] * NC + c];
    float nrm = rsqrtf((float)(dg > 1 ? dg : 1));
    out_x[(size_t)node * NC + c] = sum * nrm + b2[c];
}

// ---------------------------------------------------------------------------
// LPA
__global__ void lpa_init(const float* __restrict__ labels, const void* mask,
                         const int* __restrict__ flag, float* __restrict__ y) {
    int g = blockIdx.x * blockDim.x + threadIdx.x;
    if (g >= Nn * NC) return;
    int node = g / NC;
    int fmt = *flag;
    bool m = read_mask(mask, node, fmt);
    y[g] = m ? labels[g] : 0.f;
}

// y_next[i,c] = mask[i] ? labels[i,c] : sum_{e: src=i} y_cur[dst_e, c]
__global__ __launch_bounds__(320) void lpa_step(
    const float* __restrict__ ycur, const float* __restrict__ labels,
    const void* mask, const int* __restrict__ flag,
    const int* __restrict__ adj_src, const int* __restrict__ cnt_src,
    float* __restrict__ ynext) {
    int tid = threadIdx.x;
    int node = blockIdx.x * 8 + tid / NC;
    int c = tid % NC;
    int fmt = *flag;
    bool m = read_mask(mask, node, fmt);
    float v;
    if (m) {
        v = labels[(size_t)node * NC + c];
    } else {
        int dg = cnt_src[node];
        int cnt = dg < CAP ? dg : CAP;
        const int* lst = adj_src + (size_t)node * CAP;
        float s = 0.f;
        for (int e = 0; e < cnt; e++) s += ycur[(size_t)lst[e] * NC + c];
        v = s;
    }
    ynext[(size_t)node * NC + c] = v;
}

// ---------------------------------------------------------------------------
extern "C" void kernel_launch(void* const* d_in, const int* in_sizes, int n_in,
                              void* d_out, int out_size, void* d_ws, size_t ws_size,
                              hipStream_t stream) {
    const float* feat   = (const float*)d_in[0];
    const float* labels = (const float*)d_in[1];
    const void*  mask   = d_in[2];
    const int*   src    = (const int*)d_in[3];
    const int*   dst    = (const int*)d_in[4];
    const float* W1     = (const float*)d_in[5];
    const float* b1     = (const float*)d_in[6];
    const float* W2     = (const float*)d_in[7];
    const float* b2     = (const float*)d_in[8];

    float* out_x = (float*)d_out;
    float* out_y = out_x + (size_t)Nn * NC;

    char* ws = (char*)d_ws;
    size_t off = 0;
    auto alloc = [&](size_t bytes) -> void* {
        void* p = ws + off;
        off += (bytes + 255) & ~(size_t)255;
        return p;
    };
    int* cnt_src = (int*)alloc((size_t)Nn * 4);
    int* cnt_dst = (int*)alloc((size_t)Nn * 4);
    int* flag    = (int*)alloc(256);
    size_t zero_bytes = off;  // cnt_src, cnt_dst, flag all zeroed in one memset
    int* adj_src = (int*)alloc((size_t)Nn * CAP * 4);
    int* adj_dst = (int*)alloc((size_t)Nn * CAP * 4);
    float* h1 = (float*)alloc((size_t)Nn * HID * 4);
    float* x1 = (float*)alloc((size_t)Nn * HID * 4);
    float* h2 = (float*)alloc((size_t)Nn * NC * 4);
    float* yA = (float*)alloc((size_t)Nn * NC * 4);
    float* yB = (float*)alloc((size_t)Nn * NC * 4);

    hipMemsetAsync(d_ws, 0, zero_bytes, stream);

    detect_fmt<<<(12500 + 255) / 256, 256, 0, stream>>>((const unsigned int*)mask, flag);
    fill_csr<<<(Ee + 255) / 256, 256, 0, stream>>>(src, dst, cnt_src, cnt_dst,
                                                   adj_src, adj_dst);
    gemm1<<<(Nn + G1_ROWS - 1) / G1_ROWS, 256, 0, stream>>>(feat, W1, cnt_src, h1);
    agg_relu1<<<(Nn + 1) / 2, 256, 0, stream>>>(h1, adj_dst, cnt_dst, b1, x1);
    gemm2<<<(Nn + 31) / 32, 320, 0, stream>>>(x1, W2, cnt_src, h2);
    agg2<<<Nn / 8, 320, 0, stream>>>(h2, adj_dst, cnt_dst, b2, out_x);

    lpa_init<<<(Nn * NC + 255) / 256, 256, 0, stream>>>(labels, mask, flag, yA);
    const float* cur = yA;
    for (int t = 0; t < LPA_ITERS; t++) {
        float* nxt = (t == LPA_ITERS - 1) ? out_y : (((t & 1) == 0) ? yB : yA);
        lpa_step<<<Nn / 8, 320, 0, stream>>>(cur, labels, mask, flag,
                                             adj_src, cnt_src, nxt);
        cur = nxt;
    }
}

// Round 3
// 561.329 us; speedup vs baseline: 1.9218x; 1.9218x over previous
//
#include <hip/hip_runtime.h>

#define Nn 50000
#define Ee 800000
#define INF_ 256
#define HID 128
#define NC 40
#define CAP 64
#define LPA_ITERS 10

// ---------------------------------------------------------------------------
// Mask format detection: mask may arrive as int32 {0,1} or packed bytes {0,1}.
__global__ void detect_fmt(const unsigned int* __restrict__ m, int* flag) {
    int i = blockIdx.x * blockDim.x + threadIdx.x;
    if (i < 12500) {
        if (m[i] > 1u) atomicOr(flag, 1);
    }
}

__device__ inline bool read_mask(const void* mask, int node, int fmt) {
    if (fmt) return ((const unsigned char*)mask)[node] != 0;
    return ((const int*)mask)[node] != 0;
}

// ---------------------------------------------------------------------------
// Build adjacency lists. cnt_* double as full degree arrays.
// adj_src (out-neighbors) is only consumed by LPA for UNMASKED nodes, so
// masked sources skip the store.
__global__ void fill_csr(const int* __restrict__ src, const int* __restrict__ dst,
                         const void* __restrict__ mask, const int* __restrict__ flag,
                         int* cnt_src, int* cnt_dst,
                         int* __restrict__ adj_src, int* __restrict__ adj_dst) {
    int e = blockIdx.x * blockDim.x + threadIdx.x;
    if (e < Ee) {
        int fmt = *flag;
        int s = src[e], d = dst[e];
        int ps = atomicAdd(&cnt_src[s], 1);
        if (ps < CAP && !read_mask(mask, s, fmt)) adj_src[s * CAP + ps] = d;
        int pd = atomicAdd(&cnt_dst[d], 1);
        if (pd < CAP) adj_dst[d * CAP + pd] = s;
    }
}

// Compact list of unmasked nodes (order nondeterministic; per-node result
// is order-independent).
__global__ void build_unmasked(const void* __restrict__ mask,
                               const int* __restrict__ flag,
                               int* n_un, int* __restrict__ ulist) {
    int i = blockIdx.x * blockDim.x + threadIdx.x;
    if (i < Nn) {
        if (!read_mask(mask, i, *flag)) {
            int p = atomicAdd(n_un, 1);
            ulist[p] = i;
        }
    }
}

// ---------------------------------------------------------------------------
// GEMM1: h1[n, j] = (sum_k feat[n,k] * W1[k,j]) * norm_src[n]
#define G1_ROWS 64
#define G1_KT 32
__global__ __launch_bounds__(256) void gemm1(
    const float* __restrict__ feat, const float* __restrict__ W1,
    const int* __restrict__ cnt_src, float* __restrict__ h1) {
    __shared__ float lA[G1_ROWS][G1_KT + 1];
    __shared__ float lB[G1_KT][HID];
    const int tid = threadIdx.x;
    const int row0 = blockIdx.x * G1_ROWS;
    const int r0 = (tid >> 4) * 4;
    const int c0 = (tid & 15) * 8;

    float acc[4][8];
#pragma unroll
    for (int i = 0; i < 4; i++)
#pragma unroll
        for (int j = 0; j < 8; j++) acc[i][j] = 0.f;

    for (int k0 = 0; k0 < INF_; k0 += G1_KT) {
#pragma unroll
        for (int p = 0; p < 2; p++) {
            int idx = tid + p * 256;
            int r = idx >> 3, c4 = idx & 7;
            int grow = row0 + r;
            float4 v = make_float4(0.f, 0.f, 0.f, 0.f);
            if (grow < Nn)
                v = *(const float4*)(feat + (size_t)grow * INF_ + k0 + c4 * 4);
            lA[r][c4 * 4 + 0] = v.x;
            lA[r][c4 * 4 + 1] = v.y;
            lA[r][c4 * 4 + 2] = v.z;
            lA[r][c4 * 4 + 3] = v.w;
        }
#pragma unroll
        for (int p = 0; p < 4; p++) {
            int idx = tid + p * 256;
            int kb = idx >> 5, c4 = idx & 31;
            *(float4*)(&lB[kb][c4 * 4]) =
                *(const float4*)(W1 + (size_t)(k0 + kb) * HID + c4 * 4);
        }
        __syncthreads();
#pragma unroll 8
        for (int k = 0; k < G1_KT; k++) {
            float a[4];
#pragma unroll
            for (int i = 0; i < 4; i++) a[i] = lA[r0 + i][k];
            float4 bv0 = *(const float4*)(&lB[k][c0]);
            float4 bv1 = *(const float4*)(&lB[k][c0 + 4]);
            float b[8] = {bv0.x, bv0.y, bv0.z, bv0.w, bv1.x, bv1.y, bv1.z, bv1.w};
#pragma unroll
            for (int i = 0; i < 4; i++)
#pragma unroll
                for (int j = 0; j < 8; j++) acc[i][j] += a[i] * b[j];
        }
        __syncthreads();
    }
#pragma unroll
    for (int i = 0; i < 4; i++) {
        int grow = row0 + r0 + i;
        if (grow < Nn) {
            int dg = cnt_src[grow];
            float nrm = rsqrtf((float)(dg > 1 ? dg : 1));
            float* op = h1 + (size_t)grow * HID + c0;
#pragma unroll
            for (int j = 0; j < 8; j++) op[j] = acc[i][j] * nrm;
        }
    }
}

// ---------------------------------------------------------------------------
// agg1: x1[i,:] = relu( norm_dst[i] * sum_{e: dst=i} h1[src_e,:] + b1 )
// 8 nodes/block, 32 lanes/node, float4 gathers, 4-edge unroll.
__global__ __launch_bounds__(256) void agg_relu1(
    const float4* __restrict__ h1, const int* __restrict__ adj_dst,
    const int* __restrict__ cnt_dst, const float4* __restrict__ b1,
    float4* __restrict__ x1) {
    int node = blockIdx.x * 8 + (threadIdx.x >> 5);
    int l = threadIdx.x & 31;
    int dg = cnt_dst[node];
    int cnt = dg < CAP ? dg : CAP;
    const int* lst = adj_dst + (size_t)node * CAP;
    float4 s = make_float4(0.f, 0.f, 0.f, 0.f);
    int e = 0;
    for (; e + 4 <= cnt; e += 4) {
        int i0 = lst[e], i1 = lst[e + 1], i2 = lst[e + 2], i3 = lst[e + 3];
        float4 a = h1[(size_t)i0 * 32 + l];
        float4 b = h1[(size_t)i1 * 32 + l];
        float4 c = h1[(size_t)i2 * 32 + l];
        float4 d = h1[(size_t)i3 * 32 + l];
        s.x += (a.x + b.x) + (c.x + d.x);
        s.y += (a.y + b.y) + (c.y + d.y);
        s.z += (a.z + b.z) + (c.z + d.z);
        s.w += (a.w + b.w) + (c.w + d.w);
    }
    for (; e < cnt; e++) {
        float4 a = h1[(size_t)lst[e] * 32 + l];
        s.x += a.x; s.y += a.y; s.z += a.z; s.w += a.w;
    }
    float nrm = rsqrtf((float)(dg > 1 ? dg : 1));
    float4 bb = b1[l];
    float4 v;
    v.x = fmaxf(s.x * nrm + bb.x, 0.f);
    v.y = fmaxf(s.y * nrm + bb.y, 0.f);
    v.z = fmaxf(s.z * nrm + bb.z, 0.f);
    v.w = fmaxf(s.w * nrm + bb.w, 0.f);
    x1[(size_t)node * 32 + l] = v;
}

// ---------------------------------------------------------------------------
// GEMM2: h2[n,c] = (sum_k x1[n,k] * W2[k,c]) * norm_src[n]
__global__ __launch_bounds__(320) void gemm2(
    const float* __restrict__ x1, const float* __restrict__ W2,
    const int* __restrict__ cnt_src, float* __restrict__ h2) {
    int tid = threadIdx.x;
    int c = tid % NC;
    int rg = tid / NC;
    int row0 = blockIdx.x * 32 + rg * 4;
    int rc[4];
#pragma unroll
    for (int i = 0; i < 4; i++) {
        int r = row0 + i;
        rc[i] = r < Nn ? r : Nn - 1;
    }
    float acc[4] = {0.f, 0.f, 0.f, 0.f};
    for (int k = 0; k < HID; k++) {
        float w = W2[(size_t)k * NC + c];
#pragma unroll
        for (int i = 0; i < 4; i++) acc[i] += x1[(size_t)rc[i] * HID + k] * w;
    }
#pragma unroll
    for (int i = 0; i < 4; i++) {
        int r = row0 + i;
        if (r < Nn) {
            int dg = cnt_src[r];
            float nrm = rsqrtf((float)(dg > 1 ? dg : 1));
            h2[(size_t)r * NC + c] = acc[i] * nrm;
        }
    }
}

// ---------------------------------------------------------------------------
// agg2: out_x[i,c] = norm_dst[i] * sum_{e: dst=i} h2[src_e,c] + b2[c]
// 32 nodes/block, 10 lanes/node, float4 gathers, 4-edge unroll.
__global__ __launch_bounds__(320) void agg2(
    const float4* __restrict__ h2, const int* __restrict__ adj_dst,
    const int* __restrict__ cnt_dst, const float4* __restrict__ b2,
    float4* __restrict__ out_x) {
    int node = blockIdx.x * 32 + threadIdx.x / 10;
    int l = threadIdx.x % 10;
    if (node >= Nn) return;
    int dg = cnt_dst[node];
    int cnt = dg < CAP ? dg : CAP;
    const int* lst = adj_dst + (size_t)node * CAP;
    float4 s = make_float4(0.f, 0.f, 0.f, 0.f);
    int e = 0;
    for (; e + 4 <= cnt; e += 4) {
        int i0 = lst[e], i1 = lst[e + 1], i2 = lst[e + 2], i3 = lst[e + 3];
        float4 a = h2[(size_t)i0 * 10 + l];
        float4 b = h2[(size_t)i1 * 10 + l];
        float4 c = h2[(size_t)i2 * 10 + l];
        float4 d = h2[(size_t)i3 * 10 + l];
        s.x += (a.x + b.x) + (c.x + d.x);
        s.y += (a.y + b.y) + (c.y + d.y);
        s.z += (a.z + b.z) + (c.z + d.z);
        s.w += (a.w + b.w) + (c.w + d.w);
    }
    for (; e < cnt; e++) {
        float4 a = h2[(size_t)lst[e] * 10 + l];
        s.x += a.x; s.y += a.y; s.z += a.z; s.w += a.w;
    }
    float nrm = rsqrtf((float)(dg > 1 ? dg : 1));
    float4 bb = b2[l];
    float4 v;
    v.x = s.x * nrm + bb.x;
    v.y = s.y * nrm + bb.y;
    v.z = s.z * nrm + bb.z;
    v.w = s.w * nrm + bb.w;
    out_x[(size_t)node * 10 + l] = v;
}

// ---------------------------------------------------------------------------
// LPA. Masked rows are constant (= labels): pre-fill them in yA, yB, out_y
// once; steps touch only unmasked rows via the compacted list.
__global__ void lpa_init(const float* __restrict__ labels, const void* mask,
                         const int* __restrict__ flag,
                         float* __restrict__ yA, float* __restrict__ yB,
                         float* __restrict__ out_y) {
    int g = blockIdx.x * blockDim.x + threadIdx.x;
    if (g >= Nn * NC) return;
    int node = g / NC;
    bool m = read_mask(mask, node, *flag);
    float lv = labels[g];
    yA[g] = m ? lv : 0.f;
    if (m) {
        yB[g] = lv;
        out_y[g] = lv;
    }
}

// y_next[u,:] = sum_{e: src=u} y_cur[dst_e, :]  for unmasked u only.
// 32 nodes/block, 10 lanes/node, float4, 4-edge unroll.
__global__ __launch_bounds__(320) void lpa_step(
    const float4* __restrict__ ycur, const int* __restrict__ n_un,
    const int* __restrict__ ulist, const int* __restrict__ adj_src,
    const int* __restrict__ cnt_src, float4* __restrict__ ynext) {
    int g = blockIdx.x * 32 + threadIdx.x / 10;
    int l = threadIdx.x % 10;
    if (g >= *n_un) return;
    int u = ulist[g];
    int dg = cnt_src[u];
    int cnt = dg < CAP ? dg : CAP;
    const int* lst = adj_src + (size_t)u * CAP;
    float4 s = make_float4(0.f, 0.f, 0.f, 0.f);
    int e = 0;
    for (; e + 4 <= cnt; e += 4) {
        int i0 = lst[e], i1 = lst[e + 1], i2 = lst[e + 2], i3 = lst[e + 3];
        float4 a = ycur[(size_t)i0 * 10 + l];
        float4 b = ycur[(size_t)i1 * 10 + l];
        float4 c = ycur[(size_t)i2 * 10 + l];
        float4 d = ycur[(size_t)i3 * 10 + l];
        s.x += (a.x + b.x) + (c.x + d.x);
        s.y += (a.y + b.y) + (c.y + d.y);
        s.z += (a.z + b.z) + (c.z + d.z);
        s.w += (a.w + b.w) + (c.w + d.w);
    }
    for (; e < cnt; e++) {
        float4 a = ycur[(size_t)lst[e] * 10 + l];
        s.x += a.x; s.y += a.y; s.z += a.z; s.w += a.w;
    }
    ynext[(size_t)u * 10 + l] = s;
}

// ---------------------------------------------------------------------------
extern "C" void kernel_launch(void* const* d_in, const int* in_sizes, int n_in,
                              void* d_out, int out_size, void* d_ws, size_t ws_size,
                              hipStream_t stream) {
    const float* feat   = (const float*)d_in[0];
    const float* labels = (const float*)d_in[1];
    const void*  mask   = d_in[2];
    const int*   src    = (const int*)d_in[3];
    const int*   dst    = (const int*)d_in[4];
    const float* W1     = (const float*)d_in[5];
    const float* b1     = (const float*)d_in[6];
    const float* W2     = (const float*)d_in[7];
    const float* b2     = (const float*)d_in[8];

    float* out_x = (float*)d_out;
    float* out_y = out_x + (size_t)Nn * NC;

    char* ws = (char*)d_ws;
    size_t off = 0;
    auto alloc = [&](size_t bytes) -> void* {
        void* p = ws + off;
        off += (bytes + 255) & ~(size_t)255;
        return p;
    };
    int* cnt_src = (int*)alloc((size_t)Nn * 4);
    int* cnt_dst = (int*)alloc((size_t)Nn * 4);
    int* flag    = (int*)alloc(256);   // flag[0]=fmt flag, flag[1]=n_un
    int* n_un    = flag + 1;           // (flag+64 was +256 BYTES -> aliased ulist!)
    size_t zero_bytes = off;           // zero cnt_src, cnt_dst, flag block
    int* ulist   = (int*)alloc((size_t)Nn * 4);
    int* adj_src = (int*)alloc((size_t)Nn * CAP * 4);
    int* adj_dst = (int*)alloc((size_t)Nn * CAP * 4);
    float* h1 = (float*)alloc((size_t)Nn * HID * 4);
    float* x1 = (float*)alloc((size_t)Nn * HID * 4);
    float* h2 = (float*)alloc((size_t)Nn * NC * 4);
    float* yA = (float*)alloc((size_t)Nn * NC * 4);
    float* yB = (float*)alloc((size_t)Nn * NC * 4);

    hipMemsetAsync(d_ws, 0, zero_bytes, stream);

    detect_fmt<<<(12500 + 255) / 256, 256, 0, stream>>>((const unsigned int*)mask, flag);
    fill_csr<<<(Ee + 255) / 256, 256, 0, stream>>>(src, dst, mask, flag,
                                                   cnt_src, cnt_dst, adj_src, adj_dst);
    build_unmasked<<<(Nn + 255) / 256, 256, 0, stream>>>(mask, flag, n_un, ulist);
    gemm1<<<(Nn + G1_ROWS - 1) / G1_ROWS, 256, 0, stream>>>(feat, W1, cnt_src, h1);
    agg_relu1<<<Nn / 8, 256, 0, stream>>>((const float4*)h1, adj_dst, cnt_dst,
                                          (const float4*)b1, (float4*)x1);
    gemm2<<<(Nn + 31) / 32, 320, 0, stream>>>(x1, W2, cnt_src, h2);
    agg2<<<(Nn + 31) / 32, 320, 0, stream>>>((const float4*)h2, adj_dst, cnt_dst,
                                             (const float4*)b2, (float4*)out_x);

    lpa_init<<<(Nn * NC + 255) / 256, 256, 0, stream>>>(labels, mask, flag, yA, yB, out_y);
    const float* cur = yA;
    for (int t = 0; t < LPA_ITERS; t++) {
        float* nxt = (t == LPA_ITERS - 1) ? out_y : (((t & 1) == 0) ? yB : yA);
        lpa_step<<<(Nn + 31) / 32, 320, 0, stream>>>(
            (const float4*)cur, n_un, ulist, adj_src, cnt_src, (float4*)nxt);
        cur = (const float*)nxt;
    }
}

// Round 4
// 561.018 us; speedup vs baseline: 1.9228x; 1.0006x over previous
//
#include <hip/hip_runtime.h>

#define Nn 50000
#define Ee 800000
#define INF_ 256
#define HID 128
#define NC 40
#define CAPD 48      // adj_dst row capacity (in-degree; Poisson(16) tail @48 ~1e-11)
#define CAPS 48      // adj_s row capacity (u-list front, m-list back)
#define LPA_ITERS 10
#define NB 98        // dst/src buckets of 512 nodes
#define BSH 9
#define EPB 8192     // edges per bin_edges block

// ---------------------------------------------------------------------------
__global__ void detect_fmt(const unsigned int* __restrict__ m, int* flag) {
    int i = blockIdx.x * blockDim.x + threadIdx.x;
    if (i < 12500) {
        if (m[i] > 1u) atomicOr(flag, 1);
    }
}

__device__ inline bool read_mask(const void* mask, int node, int fmt) {
    if (fmt) return ((const unsigned char*)mask)[node] != 0;
    return ((const int*)mask)[node] != 0;
}

// ---------------------------------------------------------------------------
// A0: per-bucket global histograms (dst: all edges; src: unmasked src only)
// + full out-degree histogram cnt_src (fire-and-forget atomics).
__global__ __launch_bounds__(256) void hist_buckets(
    const int* __restrict__ src, const int* __restrict__ dst,
    const void* __restrict__ mask, const int* __restrict__ flag,
    int* __restrict__ cnt_src, int* __restrict__ ghist_d, int* __restrict__ ghist_s) {
    __shared__ int hd[NB], hs[NB];
    int tid = threadIdx.x;
    if (tid < NB) { hd[tid] = 0; hs[tid] = 0; }
    __syncthreads();
    int fmt = *flag;
    int e0 = blockIdx.x * 1024;
#pragma unroll
    for (int k = 0; k < 4; k++) {
        int e = e0 + tid + k * 256;
        if (e < Ee) {
            int s = src[e], d = dst[e];
            atomicAdd(&cnt_src[s], 1);
            atomicAdd(&hd[d >> BSH], 1);
            if (!read_mask(mask, s, fmt)) atomicAdd(&hs[s >> BSH], 1);
        }
    }
    __syncthreads();
    if (tid < NB) {
        if (hd[tid]) atomicAdd(&ghist_d[tid], hd[tid]);
        if (hs[tid]) atomicAdd(&ghist_s[tid], hs[tid]);
    }
}

// exclusive scan of bucket histograms -> base, and init cursors = base
__global__ void scan_buckets(const int* __restrict__ gd, const int* __restrict__ gs,
                             int* based, int* bases, int* curd, int* curs) {
    if (threadIdx.x == 0) {
        int run = 0;
        for (int b = 0; b < NB; b++) { based[b] = run; curd[b] = run; run += gd[b]; }
        based[NB] = run;
        run = 0;
        for (int b = 0; b < NB; b++) { bases[b] = run; curs[b] = run; run += gs[b]; }
        bases[NB] = run;
    }
}

// Phase A: bin edges into bucket arrays as packed (hi<<16)|lo records,
// LDS-staged so global writes are coalesced per-bucket bursts.
__global__ __launch_bounds__(256) void bin_edges(
    const int* __restrict__ src, const int* __restrict__ dst,
    const void* __restrict__ mask, const int* __restrict__ flag,
    int* __restrict__ cur_d, int* __restrict__ cur_s,
    unsigned* __restrict__ bkt_d, unsigned* __restrict__ bkt_s) {
    __shared__ unsigned stage[EPB];
    __shared__ int hist[NB], off[NB], baseL[NB], curL[NB];
    int tid = threadIdx.x;
    int e0 = blockIdx.x * EPB;
    int fmt = *flag;

    // ---------------- DST direction (all edges) ----------------
    if (tid < NB) hist[tid] = 0;
    __syncthreads();
#pragma unroll
    for (int k = 0; k < EPB / 256; k++) {
        int e = e0 + tid + k * 256;
        if (e < Ee) atomicAdd(&hist[dst[e] >> BSH], 1);
    }
    __syncthreads();
    if (tid == 0) {
        int run = 0;
        for (int b = 0; b < NB; b++) { off[b] = run; run += hist[b]; }
    }
    __syncthreads();
    if (tid < NB) {
        baseL[tid] = hist[tid] ? atomicAdd(&cur_d[tid], hist[tid]) : 0;
        curL[tid] = off[tid];
    }
    __syncthreads();
#pragma unroll
    for (int k = 0; k < EPB / 256; k++) {
        int e = e0 + tid + k * 256;
        if (e < Ee) {
            int s = src[e], d = dst[e];
            int p = atomicAdd(&curL[d >> BSH], 1);
            stage[p] = ((unsigned)d << 16) | (unsigned)s;
        }
    }
    __syncthreads();
    for (int b = 0; b < NB; b++) {
        int len = hist[b], gb = baseL[b], lo = off[b];
        for (int i = tid; i < len; i += 256) bkt_d[gb + i] = stage[lo + i];
    }
    __syncthreads();

    // ---------------- SRC direction (unmasked src only) ----------------
    if (tid < NB) hist[tid] = 0;
    __syncthreads();
#pragma unroll
    for (int k = 0; k < EPB / 256; k++) {
        int e = e0 + tid + k * 256;
        if (e < Ee) {
            int s = src[e];
            if (!read_mask(mask, s, fmt)) atomicAdd(&hist[s >> BSH], 1);
        }
    }
    __syncthreads();
    if (tid == 0) {
        int run = 0;
        for (int b = 0; b < NB; b++) { off[b] = run; run += hist[b]; }
    }
    __syncthreads();
    if (tid < NB) {
        baseL[tid] = hist[tid] ? atomicAdd(&cur_s[tid], hist[tid]) : 0;
        curL[tid] = off[tid];
    }
    __syncthreads();
#pragma unroll
    for (int k = 0; k < EPB / 256; k++) {
        int e = e0 + tid + k * 256;
        if (e < Ee) {
            int s = src[e];
            if (!read_mask(mask, s, fmt)) {
                int d = dst[e];
                int p = atomicAdd(&curL[s >> BSH], 1);
                stage[p] = ((unsigned)s << 16) | (unsigned)d;
            }
        }
    }
    __syncthreads();
    for (int b = 0; b < NB; b++) {
        int len = hist[b], gb = baseL[b], lo = off[b];
        for (int i = tid; i < len; i += 256) bkt_s[gb + i] = stage[lo + i];
    }
}

// Phase B (dst): one block per bucket; LDS slot counters; scattered stores
// confined to this bucket's 512*CAPD*4 = 96KB single-writer region.
__global__ __launch_bounds__(256) void build_csr_dst(
    const unsigned* __restrict__ bkt, const int* __restrict__ base,
    const int* __restrict__ ghist, int* __restrict__ adj, int* __restrict__ cnt) {
    __shared__ int lc[512];
    int b = blockIdx.x, tid = threadIdx.x;
    lc[tid] = 0; lc[tid + 256] = 0;
    __syncthreads();
    int lo = base[b], n = ghist[b], n0 = b << BSH;
    for (int i = tid; i < n; i += 256) {
        unsigned r = bkt[lo + i];
        int d = r >> 16, s = r & 0xffff;
        int sl = atomicAdd(&lc[d - n0], 1);
        if (sl < CAPD) adj[d * CAPD + sl] = s;
    }
    __syncthreads();
    int g0 = n0 + tid;
    if (g0 < Nn) cnt[g0] = lc[tid];
    g0 += 256;
    if (g0 < Nn) cnt[g0] = lc[tid + 256];
}

// Phase B (src): split each unmasked node's out-neighbors by mask[dst]:
// unmasked dst -> front of row (per-iter LPA gather), masked dst -> back
// of row (folded once into S_const).
__global__ __launch_bounds__(256) void build_csr_src(
    const unsigned* __restrict__ bkt, const int* __restrict__ base,
    const int* __restrict__ ghist, const void* __restrict__ mask,
    const int* __restrict__ flag, int* __restrict__ adj,
    int* __restrict__ cnt_u, int* __restrict__ cnt_m) {
    __shared__ int lu[512], lm[512];
    int b = blockIdx.x, tid = threadIdx.x;
    lu[tid] = 0; lu[tid + 256] = 0; lm[tid] = 0; lm[tid + 256] = 0;
    __syncthreads();
    int fmt = *flag;
    int lo = base[b], n = ghist[b], n0 = b << BSH;
    for (int i = tid; i < n; i += 256) {
        unsigned r = bkt[lo + i];
        int s = r >> 16, d = r & 0xffff;
        if (read_mask(mask, d, fmt)) {
            int sl = atomicAdd(&lm[s - n0], 1);
            if (sl < CAPS) adj[s * CAPS + (CAPS - 1 - sl)] = d;
        } else {
            int sl = atomicAdd(&lu[s - n0], 1);
            if (sl < CAPS) adj[s * CAPS + sl] = d;
        }
    }
    __syncthreads();
    int g0 = n0 + tid;
    if (g0 < Nn) { cnt_u[g0] = lu[tid]; cnt_m[g0] = lm[tid]; }
    g0 += 256;
    if (g0 < Nn) { cnt_u[g0] = lu[tid + 256]; cnt_m[g0] = lm[tid + 256]; }
}

// Compact list of unmasked nodes (order nondeterministic; OK).
__global__ void build_unmasked(const void* __restrict__ mask,
                               const int* __restrict__ flag,
                               int* n_un, int* __restrict__ ulist) {
    int i = blockIdx.x * blockDim.x + threadIdx.x;
    if (i < Nn) {
        if (!read_mask(mask, i, *flag)) {
            int p = atomicAdd(n_un, 1);
            ulist[p] = i;
        }
    }
}

// ---------------------------------------------------------------------------
// GEMM1: h1[n, j] = (sum_k feat[n,k] * W1[k,j]) * norm_src[n]
#define G1_ROWS 64
#define G1_KT 32
__global__ __launch_bounds__(256) void gemm1(
    const float* __restrict__ feat, const float* __restrict__ W1,
    const int* __restrict__ cnt_src, float* __restrict__ h1) {
    __shared__ float lA[G1_ROWS][G1_KT + 1];
    __shared__ float lB[G1_KT][HID];
    const int tid = threadIdx.x;
    const int row0 = blockIdx.x * G1_ROWS;
    const int r0 = (tid >> 4) * 4;
    const int c0 = (tid & 15) * 8;

    float acc[4][8];
#pragma unroll
    for (int i = 0; i < 4; i++)
#pragma unroll
        for (int j = 0; j < 8; j++) acc[i][j] = 0.f;

    for (int k0 = 0; k0 < INF_; k0 += G1_KT) {
#pragma unroll
        for (int p = 0; p < 2; p++) {
            int idx = tid + p * 256;
            int r = idx >> 3, c4 = idx & 7;
            int grow = row0 + r;
            float4 v = make_float4(0.f, 0.f, 0.f, 0.f);
            if (grow < Nn)
                v = *(const float4*)(feat + (size_t)grow * INF_ + k0 + c4 * 4);
            lA[r][c4 * 4 + 0] = v.x;
            lA[r][c4 * 4 + 1] = v.y;
            lA[r][c4 * 4 + 2] = v.z;
            lA[r][c4 * 4 + 3] = v.w;
        }
#pragma unroll
        for (int p = 0; p < 4; p++) {
            int idx = tid + p * 256;
            int kb = idx >> 5, c4 = idx & 31;
            *(float4*)(&lB[kb][c4 * 4]) =
                *(const float4*)(W1 + (size_t)(k0 + kb) * HID + c4 * 4);
        }
        __syncthreads();
#pragma unroll 8
        for (int k = 0; k < G1_KT; k++) {
            float a[4];
#pragma unroll
            for (int i = 0; i < 4; i++) a[i] = lA[r0 + i][k];
            float4 bv0 = *(const float4*)(&lB[k][c0]);
            float4 bv1 = *(const float4*)(&lB[k][c0 + 4]);
            float b[8] = {bv0.x, bv0.y, bv0.z, bv0.w, bv1.x, bv1.y, bv1.z, bv1.w};
#pragma unroll
            for (int i = 0; i < 4; i++)
#pragma unroll
                for (int j = 0; j < 8; j++) acc[i][j] += a[i] * b[j];
        }
        __syncthreads();
    }
#pragma unroll
    for (int i = 0; i < 4; i++) {
        int grow = row0 + r0 + i;
        if (grow < Nn) {
            int dg = cnt_src[grow];
            float nrm = rsqrtf((float)(dg > 1 ? dg : 1));
            float* op = h1 + (size_t)grow * HID + c0;
#pragma unroll
            for (int j = 0; j < 8; j++) op[j] = acc[i][j] * nrm;
        }
    }
}

// ---------------------------------------------------------------------------
// agg1: x1[i,:] = relu( norm_dst[i] * sum_{e: dst=i} h1[src_e,:] + b1 )
// 8 nodes/block, 32 lanes/node, float4 gathers, 8-edge unroll.
__global__ __launch_bounds__(256) void agg_relu1(
    const float4* __restrict__ h1, const int* __restrict__ adj_dst,
    const int* __restrict__ cnt_dst, const float4* __restrict__ b1,
    float4* __restrict__ x1) {
    int node = blockIdx.x * 8 + (threadIdx.x >> 5);
    int l = threadIdx.x & 31;
    int dg = cnt_dst[node];
    int cnt = dg < CAPD ? dg : CAPD;
    const int* lst = adj_dst + (size_t)node * CAPD;
    float4 s = make_float4(0.f, 0.f, 0.f, 0.f);
    int e = 0;
    for (; e + 8 <= cnt; e += 8) {
        float4 v[8];
#pragma unroll
        for (int q = 0; q < 8; q++) v[q] = h1[(size_t)lst[e + q] * 32 + l];
#pragma unroll
        for (int q = 0; q < 8; q++) {
            s.x += v[q].x; s.y += v[q].y; s.z += v[q].z; s.w += v[q].w;
        }
    }
    for (; e < cnt; e++) {
        float4 a = h1[(size_t)lst[e] * 32 + l];
        s.x += a.x; s.y += a.y; s.z += a.z; s.w += a.w;
    }
    float nrm = rsqrtf((float)(dg > 1 ? dg : 1));
    float4 bb = b1[l];
    float4 v;
    v.x = fmaxf(s.x * nrm + bb.x, 0.f);
    v.y = fmaxf(s.y * nrm + bb.y, 0.f);
    v.z = fmaxf(s.z * nrm + bb.z, 0.f);
    v.w = fmaxf(s.w * nrm + bb.w, 0.f);
    x1[(size_t)node * 32 + l] = v;
}

// ---------------------------------------------------------------------------
// GEMM2: h2[n,c] = (sum_k x1[n,k] * W2[k,c]) * norm_src[n]
__global__ __launch_bounds__(320) void gemm2(
    const float* __restrict__ x1, const float* __restrict__ W2,
    const int* __restrict__ cnt_src, float* __restrict__ h2) {
    int tid = threadIdx.x;
    int c = tid % NC;
    int rg = tid / NC;
    int row0 = blockIdx.x * 32 + rg * 4;
    int rc[4];
#pragma unroll
    for (int i = 0; i < 4; i++) {
        int r = row0 + i;
        rc[i] = r < Nn ? r : Nn - 1;
    }
    float acc[4] = {0.f, 0.f, 0.f, 0.f};
    for (int k = 0; k < HID; k++) {
        float w = W2[(size_t)k * NC + c];
#pragma unroll
        for (int i = 0; i < 4; i++) acc[i] += x1[(size_t)rc[i] * HID + k] * w;
    }
#pragma unroll
    for (int i = 0; i < 4; i++) {
        int r = row0 + i;
        if (r < Nn) {
            int dg = cnt_src[r];
            float nrm = rsqrtf((float)(dg > 1 ? dg : 1));
            h2[(size_t)r * NC + c] = acc[i] * nrm;
        }
    }
}

// ---------------------------------------------------------------------------
// agg2: out_x[i,c] = norm_dst[i] * sum_{e: dst=i} h2[src_e,c] + b2[c]
__global__ __launch_bounds__(320) void agg2(
    const float4* __restrict__ h2, const int* __restrict__ adj_dst,
    const int* __restrict__ cnt_dst, const float4* __restrict__ b2,
    float4* __restrict__ out_x) {
    int node = blockIdx.x * 32 + threadIdx.x / 10;
    int l = threadIdx.x % 10;
    if (node >= Nn) return;
    int dg = cnt_dst[node];
    int cnt = dg < CAPD ? dg : CAPD;
    const int* lst = adj_dst + (size_t)node * CAPD;
    float4 s = make_float4(0.f, 0.f, 0.f, 0.f);
    int e = 0;
    for (; e + 4 <= cnt; e += 4) {
        int i0 = lst[e], i1 = lst[e + 1], i2 = lst[e + 2], i3 = lst[e + 3];
        float4 a = h2[(size_t)i0 * 10 + l];
        float4 b = h2[(size_t)i1 * 10 + l];
        float4 c = h2[(size_t)i2 * 10 + l];
        float4 d = h2[(size_t)i3 * 10 + l];
        s.x += (a.x + b.x) + (c.x + d.x);
        s.y += (a.y + b.y) + (c.y + d.y);
        s.z += (a.z + b.z) + (c.z + d.z);
        s.w += (a.w + b.w) + (c.w + d.w);
    }
    for (; e < cnt; e++) {
        float4 a = h2[(size_t)lst[e] * 10 + l];
        s.x += a.x; s.y += a.y; s.z += a.z; s.w += a.w;
    }
    float nrm = rsqrtf((float)(dg > 1 ? dg : 1));
    float4 bb = b2[l];
    float4 v;
    v.x = s.x * nrm + bb.x;
    v.y = s.y * nrm + bb.y;
    v.z = s.z * nrm + bb.z;
    v.w = s.w * nrm + bb.w;
    out_x[(size_t)node * 10 + l] = v;
}

// ---------------------------------------------------------------------------
// LPA. y_t[u] = S_const[u] + sum_{unmasked nbr v} y_{t-1}[v]; y_1 == S_const,
// so run lpa_const once then 9 steps. Masked rows of out_y = labels (final).
__global__ void lpa_init(const float* __restrict__ labels, const void* mask,
                         const int* __restrict__ flag, float* __restrict__ out_y) {
    int g = blockIdx.x * blockDim.x + threadIdx.x;
    if (g >= Nn * NC) return;
    int node = g / NC;
    if (read_mask(mask, node, *flag)) out_y[g] = labels[g];
}

// S_const[u,:] = sum over masked out-neighbors (back of adj_s row) of labels.
__global__ __launch_bounds__(320) void lpa_const(
    const float4* __restrict__ labels, const int* __restrict__ n_un,
    const int* __restrict__ ulist, const int* __restrict__ adj_s,
    const int* __restrict__ cnt_m, float4* __restrict__ sconst) {
    int g = blockIdx.x * 32 + threadIdx.x / 10;
    int l = threadIdx.x % 10;
    if (g >= *n_un) return;
    int u = ulist[g];
    int cm = cnt_m[u];
    int cnt = cm < CAPS ? cm : CAPS;
    const int* lst = adj_s + (size_t)u * CAPS + (CAPS - cnt);
    float4 s = make_float4(0.f, 0.f, 0.f, 0.f);
    int e = 0;
    for (; e + 4 <= cnt; e += 4) {
        int i0 = lst[e], i1 = lst[e + 1], i2 = lst[e + 2], i3 = lst[e + 3];
        float4 a = labels[(size_t)i0 * 10 + l];
        float4 b = labels[(size_t)i1 * 10 + l];
        float4 c = labels[(size_t)i2 * 10 + l];
        float4 d = labels[(size_t)i3 * 10 + l];
        s.x += (a.x + b.x) + (c.x + d.x);
        s.y += (a.y + b.y) + (c.y + d.y);
        s.z += (a.z + b.z) + (c.z + d.z);
        s.w += (a.w + b.w) + (c.w + d.w);
    }
    for (; e < cnt; e++) {
        float4 a = labels[(size_t)lst[e] * 10 + l];
        s.x += a.x; s.y += a.y; s.z += a.z; s.w += a.w;
    }
    sconst[(size_t)u * 10 + l] = s;
}

__global__ __launch_bounds__(320) void lpa_step(
    const float4* __restrict__ ycur, const int* __restrict__ n_un,
    const int* __restrict__ ulist, const int* __restrict__ adj_s,
    const int* __restrict__ cnt_u, const float4* __restrict__ sconst,
    float4* __restrict__ ynext) {
    int g = blockIdx.x * 32 + threadIdx.x / 10;
    int l = threadIdx.x % 10;
    if (g >= *n_un) return;
    int u = ulist[g];
    int cu = cnt_u[u];
    int cnt = cu < CAPS ? cu : CAPS;
    const int* lst = adj_s + (size_t)u * CAPS;
    float4 s = sconst[(size_t)u * 10 + l];
    int e = 0;
    for (; e + 4 <= cnt; e += 4) {
        int i0 = lst[e], i1 = lst[e + 1], i2 = lst[e + 2], i3 = lst[e + 3];
        float4 a = ycur[(size_t)i0 * 10 + l];
        float4 b = ycur[(size_t)i1 * 10 + l];
        float4 c = ycur[(size_t)i2 * 10 + l];
        float4 d = ycur[(size_t)i3 * 10 + l];
        s.x += (a.x + b.x) + (c.x + d.x);
        s.y += (a.y + b.y) + (c.y + d.y);
        s.z += (a.z + b.z) + (c.z + d.z);
        s.w += (a.w + b.w) + (c.w + d.w);
    }
    for (; e < cnt; e++) {
        float4 a = ycur[(size_t)lst[e] * 10 + l];
        s.x += a.x; s.y += a.y; s.z += a.z; s.w += a.w;
    }
    ynext[(size_t)u * 10 + l] = s;
}

// ---------------------------------------------------------------------------
extern "C" void kernel_launch(void* const* d_in, const int* in_sizes, int n_in,
                              void* d_out, int out_size, void* d_ws, size_t ws_size,
                              hipStream_t stream) {
    const float* feat   = (const float*)d_in[0];
    const float* labels = (const float*)d_in[1];
    const void*  mask   = d_in[2];
    const int*   src    = (const int*)d_in[3];
    const int*   dst    = (const int*)d_in[4];
    const float* W1     = (const float*)d_in[5];
    const float* b1     = (const float*)d_in[6];
    const float* W2     = (const float*)d_in[7];
    const float* b2     = (const float*)d_in[8];

    float* out_x = (float*)d_out;
    float* out_y = out_x + (size_t)Nn * NC;

    char* ws = (char*)d_ws;
    size_t off = 0;
    auto alloc = [&](size_t bytes) -> void* {
        void* p = ws + off;
        off += (bytes + 255) & ~(size_t)255;
        return p;
    };
    // --- zeroed header ---
    int* flag    = (int*)alloc(256);   // flag[0]=fmt, flag[1]=n_un
    int* n_un    = flag + 1;
    int* cnt_src = (int*)alloc((size_t)Nn * 4);
    int* ghist_d = (int*)alloc(512);
    int* ghist_s = (int*)alloc(512);
    size_t zero_bytes = off;
    // --- non-zeroed header ---
    int* cnt_dst = (int*)alloc((size_t)Nn * 4);
    int* cnt_u   = (int*)alloc((size_t)Nn * 4);
    int* cnt_m   = (int*)alloc((size_t)Nn * 4);
    int* base_d  = (int*)alloc(512);
    int* base_s  = (int*)alloc(512);
    int* cur_d   = (int*)alloc(512);
    int* cur_s   = (int*)alloc(512);
    int* ulist   = (int*)alloc((size_t)Nn * 4);
    // --- big buffers; bucket arrays alias h1 (dead before gemm1 writes) ---
    char* uni = (char*)alloc((size_t)Nn * HID * 4);   // 25.6MB union region
    unsigned* bkt_d = (unsigned*)uni;                  // 3.2MB
    unsigned* bkt_s = (unsigned*)(uni + (size_t)Ee * 4); // 3.2MB
    float* h1 = (float*)uni;
    float* x1 = (float*)alloc((size_t)Nn * HID * 4);
    int* adj_s = (int*)alloc((size_t)Nn * CAPS * 4);
    int* adj_dst = (int*)alloc((size_t)Nn * CAPD * 4);
    float* h2 = (float*)alloc((size_t)Nn * NC * 4);
    float* sconst = (float*)alloc((size_t)Nn * NC * 4);
    float* yA = (float*)alloc((size_t)Nn * NC * 4);

    hipMemsetAsync(d_ws, 0, zero_bytes, stream);

    detect_fmt<<<49, 256, 0, stream>>>((const unsigned int*)mask, flag);
    hist_buckets<<<782, 256, 0, stream>>>(src, dst, mask, flag, cnt_src, ghist_d, ghist_s);
    scan_buckets<<<1, 64, 0, stream>>>(ghist_d, ghist_s, base_d, base_s, cur_d, cur_s);
    bin_edges<<<NB, 256, 0, stream>>>(src, dst, mask, flag, cur_d, cur_s, bkt_d, bkt_s);
    build_csr_dst<<<NB, 256, 0, stream>>>(bkt_d, base_d, ghist_d, adj_dst, cnt_dst);
    build_csr_src<<<NB, 256, 0, stream>>>(bkt_s, base_s, ghist_s, mask, flag,
                                          adj_s, cnt_u, cnt_m);
    build_unmasked<<<196, 256, 0, stream>>>(mask, flag, n_un, ulist);

    gemm1<<<(Nn + G1_ROWS - 1) / G1_ROWS, 256, 0, stream>>>(feat, W1, cnt_src, h1);
    agg_relu1<<<Nn / 8, 256, 0, stream>>>((const float4*)h1, adj_dst, cnt_dst,
                                          (const float4*)b1, (float4*)x1);
    gemm2<<<(Nn + 31) / 32, 320, 0, stream>>>(x1, W2, cnt_src, h2);
    agg2<<<(Nn + 31) / 32, 320, 0, stream>>>((const float4*)h2, adj_dst, cnt_dst,
                                             (const float4*)b2, (float4*)out_x);

    lpa_init<<<(Nn * NC + 255) / 256, 256, 0, stream>>>(labels, mask, flag, out_y);
    lpa_const<<<(Nn + 31) / 32, 320, 0, stream>>>(
        (const float4*)labels, n_un, ulist, adj_s, cnt_m, (float4*)sconst);
    const float* cur = sconst;
    for (int t = 1; t <= LPA_ITERS - 1; t++) {
        float* nxt = (t & 1) ? out_y : yA;   // t=9 (last) -> out_y
        lpa_step<<<(Nn + 31) / 32, 320, 0, stream>>>(
            (const float4*)cur, n_un, ulist, adj_s, cnt_u,
            (const float4*)sconst, (float4*)nxt);
        cur = nxt;
    }
}

// Round 5
// 484.292 us; speedup vs baseline: 2.2275x; 1.1584x over previous
//
#include <hip/hip_runtime.h>

#define Nn 50000
#define Ee 800000
#define INF_ 256
#define HID 128
#define NC 40
#define CAPD 48      // adj_dst row capacity (Poisson(16) tail @48 ~1e-11)
#define CAPS 48      // adj_s row capacity (u-list front, m-list back)
#define LPA_ITERS 10
#define NB 98        // node buckets of 512
#define BSH 9
#define EPB 2048     // edges per bin_edges block
#define NBLK ((Ee + EPB - 1) / EPB)   // 391
#define CAPB_D 10240 // per-bucket bin capacity, dst direction (mean 8163)
#define CAPB_S 6144  // per-bucket bin capacity, src/unmasked (mean ~4081)

// ---------------------------------------------------------------------------
__global__ void detect_fmt(const unsigned int* __restrict__ m, int* flag) {
    int i = blockIdx.x * blockDim.x + threadIdx.x;
    if (i < 12500) {
        if (m[i] > 1u) atomicOr(flag, 1);
    }
}

__device__ inline bool read_mask(const void* mask, int node, int fmt) {
    if (fmt) return ((const unsigned char*)mask)[node] != 0;
    return ((const int*)mask)[node] != 0;
}

// ---------------------------------------------------------------------------
// Single-pass edge binning, both directions, one edge read (pairs kept in
// registers). Per-block LDS staging -> coalesced bucket-run writebacks via
// flat loop + binary search. Global bins have fixed per-bucket capacity so
// no prepass/scan is needed; cur_* cursors (zeroed) reserve runs.
// Also accumulates full out-degree histogram cnt_src (fire-and-forget).
__global__ __launch_bounds__(256) void bin_edges(
    const int* __restrict__ src, const int* __restrict__ dst,
    const void* __restrict__ mask, const int* __restrict__ flag,
    int* __restrict__ cnt_src,
    int* __restrict__ cur_d, int* __restrict__ cur_s,
    unsigned* __restrict__ bkt_d, unsigned* __restrict__ bkt_s) {
    __shared__ unsigned stage_d[EPB];
    __shared__ unsigned stage_s[EPB];
    __shared__ int hd[NB], od[NB + 1], cd[NB], gd_[NB];
    __shared__ int hs[NB], os_[NB + 1], cs_[NB], gs_[NB];
    int tid = threadIdx.x;
    int e0 = blockIdx.x * EPB;
    int fmt = *flag;
    if (tid < NB) { hd[tid] = 0; hs[tid] = 0; }
    __syncthreads();

    int rs[EPB / 256], rd[EPB / 256];
    unsigned um = 0;  // bit k: src unmasked
#pragma unroll
    for (int k = 0; k < EPB / 256; k++) {
        int e = e0 + tid + k * 256;
        rs[k] = -1; rd[k] = -1;
        if (e < Ee) {
            int s = src[e], d = dst[e];
            rs[k] = s; rd[k] = d;
            atomicAdd(&cnt_src[s], 1);
            atomicAdd(&hd[d >> BSH], 1);
            if (!read_mask(mask, s, fmt)) {
                um |= (1u << k);
                atomicAdd(&hs[s >> BSH], 1);
            }
        }
    }
    __syncthreads();
    if (tid == 0) {
        int run = 0;
        for (int b = 0; b < NB; b++) { od[b] = run; run += hd[b]; }
        od[NB] = run;
        run = 0;
        for (int b = 0; b < NB; b++) { os_[b] = run; run += hs[b]; }
        os_[NB] = run;
    }
    __syncthreads();
    if (tid < NB) {
        gd_[tid] = hd[tid] ? atomicAdd(&cur_d[tid], hd[tid]) : 0;
        gs_[tid] = hs[tid] ? atomicAdd(&cur_s[tid], hs[tid]) : 0;
        cd[tid] = od[tid];
        cs_[tid] = os_[tid];
    }
    __syncthreads();
#pragma unroll
    for (int k = 0; k < EPB / 256; k++) {
        if (rd[k] >= 0) {
            int p = atomicAdd(&cd[rd[k] >> BSH], 1);
            stage_d[p] = ((unsigned)rd[k] << 16) | (unsigned)rs[k];
            if (um & (1u << k)) {
                int q = atomicAdd(&cs_[rs[k] >> BSH], 1);
                stage_s[q] = ((unsigned)rs[k] << 16) | (unsigned)rd[k];
            }
        }
    }
    __syncthreads();
    // flat coalesced writeback; binary search od[] for the bucket of index i
    int totd = od[NB];
    for (int i = tid; i < totd; i += 256) {
        int lo = 0, hi = NB;
        while (hi - lo > 1) {
            int mid = (lo + hi) >> 1;
            if (od[mid] <= i) lo = mid; else hi = mid;
        }
        int pos = gd_[lo] + (i - od[lo]);
        if (pos < CAPB_D) bkt_d[(size_t)lo * CAPB_D + pos] = stage_d[i];
    }
    int tots = os_[NB];
    for (int i = tid; i < tots; i += 256) {
        int lo = 0, hi = NB;
        while (hi - lo > 1) {
            int mid = (lo + hi) >> 1;
            if (os_[mid] <= i) lo = mid; else hi = mid;
        }
        int pos = gs_[lo] + (i - os_[lo]);
        if (pos < CAPB_S) bkt_s[(size_t)lo * CAPB_S + pos] = stage_s[i];
    }
}

// Phase B (dst): one block per bucket; LDS slot counters; scattered stores
// confined to this bucket's single-writer region.
__global__ __launch_bounds__(256) void build_csr_dst(
    const unsigned* __restrict__ bkt, const int* __restrict__ cur,
    int* __restrict__ adj, int* __restrict__ cnt) {
    __shared__ int lc[512];
    int b = blockIdx.x, tid = threadIdx.x;
    lc[tid] = 0; lc[tid + 256] = 0;
    __syncthreads();
    int n = cur[b]; if (n > CAPB_D) n = CAPB_D;
    int n0 = b << BSH;
    const unsigned* base = bkt + (size_t)b * CAPB_D;
    for (int i = tid; i < n; i += 256) {
        unsigned r = base[i];
        int d = r >> 16, s = r & 0xffff;
        int sl = atomicAdd(&lc[d - n0], 1);
        if (sl < CAPD) adj[d * CAPD + sl] = s;
    }
    __syncthreads();
    int g0 = n0 + tid;
    if (g0 < Nn) cnt[g0] = lc[tid];
    g0 += 256;
    if (g0 < Nn) cnt[g0] = lc[tid + 256];
}

// Phase B (src): split each unmasked node's out-neighbors by mask[dst]:
// unmasked dst -> row front (per-iter gather), masked dst -> row back
// (folded once into S_const).
__global__ __launch_bounds__(256) void build_csr_src(
    const unsigned* __restrict__ bkt, const int* __restrict__ cur,
    const void* __restrict__ mask, const int* __restrict__ flag,
    int* __restrict__ adj, int* __restrict__ cnt_u, int* __restrict__ cnt_m) {
    __shared__ int lu[512], lm[512];
    int b = blockIdx.x, tid = threadIdx.x;
    lu[tid] = 0; lu[tid + 256] = 0; lm[tid] = 0; lm[tid + 256] = 0;
    __syncthreads();
    int fmt = *flag;
    int n = cur[b]; if (n > CAPB_S) n = CAPB_S;
    int n0 = b << BSH;
    const unsigned* base = bkt + (size_t)b * CAPB_S;
    for (int i = tid; i < n; i += 256) {
        unsigned r = base[i];
        int s = r >> 16, d = r & 0xffff;
        if (read_mask(mask, d, fmt)) {
            int sl = atomicAdd(&lm[s - n0], 1);
            if (sl < CAPS) adj[s * CAPS + (CAPS - 1 - sl)] = d;
        } else {
            int sl = atomicAdd(&lu[s - n0], 1);
            if (sl < CAPS) adj[s * CAPS + sl] = d;
        }
    }
    __syncthreads();
    int g0 = n0 + tid;
    if (g0 < Nn) { cnt_u[g0] = lu[tid]; cnt_m[g0] = lm[tid]; }
    g0 += 256;
    if (g0 < Nn) { cnt_u[g0] = lu[tid + 256]; cnt_m[g0] = lm[tid + 256]; }
}

// Compact list of unmasked nodes (order nondeterministic; OK).
__global__ void build_unmasked(const void* __restrict__ mask,
                               const int* __restrict__ flag,
                               int* n_un, int* __restrict__ ulist) {
    int i = blockIdx.x * blockDim.x + threadIdx.x;
    if (i < Nn) {
        if (!read_mask(mask, i, *flag)) {
            int p = atomicAdd(n_un, 1);
            ulist[p] = i;
        }
    }
}

// ---------------------------------------------------------------------------
// GEMM1: h1[n, j] = (sum_k feat[n,k] * W1[k,j]) * norm_src[n]
#define G1_ROWS 64
#define G1_KT 32
__global__ __launch_bounds__(256) void gemm1(
    const float* __restrict__ feat, const float* __restrict__ W1,
    const int* __restrict__ cnt_src, float* __restrict__ h1) {
    __shared__ float lA[G1_ROWS][G1_KT + 1];
    __shared__ float lB[G1_KT][HID];
    const int tid = threadIdx.x;
    const int row0 = blockIdx.x * G1_ROWS;
    const int r0 = (tid >> 4) * 4;
    const int c0 = (tid & 15) * 8;

    float acc[4][8];
#pragma unroll
    for (int i = 0; i < 4; i++)
#pragma unroll
        for (int j = 0; j < 8; j++) acc[i][j] = 0.f;

    for (int k0 = 0; k0 < INF_; k0 += G1_KT) {
#pragma unroll
        for (int p = 0; p < 2; p++) {
            int idx = tid + p * 256;
            int r = idx >> 3, c4 = idx & 7;
            int grow = row0 + r;
            float4 v = make_float4(0.f, 0.f, 0.f, 0.f);
            if (grow < Nn)
                v = *(const float4*)(feat + (size_t)grow * INF_ + k0 + c4 * 4);
            lA[r][c4 * 4 + 0] = v.x;
            lA[r][c4 * 4 + 1] = v.y;
            lA[r][c4 * 4 + 2] = v.z;
            lA[r][c4 * 4 + 3] = v.w;
        }
#pragma unroll
        for (int p = 0; p < 4; p++) {
            int idx = tid + p * 256;
            int kb = idx >> 5, c4 = idx & 31;
            *(float4*)(&lB[kb][c4 * 4]) =
                *(const float4*)(W1 + (size_t)(k0 + kb) * HID + c4 * 4);
        }
        __syncthreads();
#pragma unroll 8
        for (int k = 0; k < G1_KT; k++) {
            float a[4];
#pragma unroll
            for (int i = 0; i < 4; i++) a[i] = lA[r0 + i][k];
            float4 bv0 = *(const float4*)(&lB[k][c0]);
            float4 bv1 = *(const float4*)(&lB[k][c0 + 4]);
            float b[8] = {bv0.x, bv0.y, bv0.z, bv0.w, bv1.x, bv1.y, bv1.z, bv1.w};
#pragma unroll
            for (int i = 0; i < 4; i++)
#pragma unroll
                for (int j = 0; j < 8; j++) acc[i][j] += a[i] * b[j];
        }
        __syncthreads();
    }
#pragma unroll
    for (int i = 0; i < 4; i++) {
        int grow = row0 + r0 + i;
        if (grow < Nn) {
            int dg = cnt_src[grow];
            float nrm = rsqrtf((float)(dg > 1 ? dg : 1));
            float* op = h1 + (size_t)grow * HID + c0;
#pragma unroll
            for (int j = 0; j < 8; j++) op[j] = acc[i][j] * nrm;
        }
    }
}

// ---------------------------------------------------------------------------
// agg1: x1[i,:] = relu( norm_dst[i] * sum_{e: dst=i} h1[src_e,:] + b1 )
__global__ __launch_bounds__(256) void agg_relu1(
    const float4* __restrict__ h1, const int* __restrict__ adj_dst,
    const int* __restrict__ cnt_dst, const float4* __restrict__ b1,
    float4* __restrict__ x1) {
    int node = blockIdx.x * 8 + (threadIdx.x >> 5);
    int l = threadIdx.x & 31;
    int dg = cnt_dst[node];
    int cnt = dg < CAPD ? dg : CAPD;
    const int* lst = adj_dst + (size_t)node * CAPD;
    float4 s = make_float4(0.f, 0.f, 0.f, 0.f);
    int e = 0;
    for (; e + 8 <= cnt; e += 8) {
        float4 v[8];
#pragma unroll
        for (int q = 0; q < 8; q++) v[q] = h1[(size_t)lst[e + q] * 32 + l];
#pragma unroll
        for (int q = 0; q < 8; q++) {
            s.x += v[q].x; s.y += v[q].y; s.z += v[q].z; s.w += v[q].w;
        }
    }
    for (; e < cnt; e++) {
        float4 a = h1[(size_t)lst[e] * 32 + l];
        s.x += a.x; s.y += a.y; s.z += a.z; s.w += a.w;
    }
    float nrm = rsqrtf((float)(dg > 1 ? dg : 1));
    float4 bb = b1[l];
    float4 v;
    v.x = fmaxf(s.x * nrm + bb.x, 0.f);
    v.y = fmaxf(s.y * nrm + bb.y, 0.f);
    v.z = fmaxf(s.z * nrm + bb.z, 0.f);
    v.w = fmaxf(s.w * nrm + bb.w, 0.f);
    x1[(size_t)node * 32 + l] = v;
}

// ---------------------------------------------------------------------------
// GEMM2: h2[n,c] = (sum_k x1[n,k] * W2[k,c]) * norm_src[n]
__global__ __launch_bounds__(320) void gemm2(
    const float* __restrict__ x1, const float* __restrict__ W2,
    const int* __restrict__ cnt_src, float* __restrict__ h2) {
    int tid = threadIdx.x;
    int c = tid % NC;
    int rg = tid / NC;
    int row0 = blockIdx.x * 32 + rg * 4;
    int rc[4];
#pragma unroll
    for (int i = 0; i < 4; i++) {
        int r = row0 + i;
        rc[i] = r < Nn ? r : Nn - 1;
    }
    float acc[4] = {0.f, 0.f, 0.f, 0.f};
    for (int k = 0; k < HID; k++) {
        float w = W2[(size_t)k * NC + c];
#pragma unroll
        for (int i = 0; i < 4; i++) acc[i] += x1[(size_t)rc[i] * HID + k] * w;
    }
#pragma unroll
    for (int i = 0; i < 4; i++) {
        int r = row0 + i;
        if (r < Nn) {
            int dg = cnt_src[r];
            float nrm = rsqrtf((float)(dg > 1 ? dg : 1));
            h2[(size_t)r * NC + c] = acc[i] * nrm;
        }
    }
}

// ---------------------------------------------------------------------------
// agg2: out_x[i,c] = norm_dst[i] * sum_{e: dst=i} h2[src_e,c] + b2[c]
__global__ __launch_bounds__(320) void agg2(
    const float4* __restrict__ h2, const int* __restrict__ adj_dst,
    const int* __restrict__ cnt_dst, const float4* __restrict__ b2,
    float4* __restrict__ out_x) {
    int node = blockIdx.x * 32 + threadIdx.x / 10;
    int l = threadIdx.x % 10;
    if (node >= Nn) return;
    int dg = cnt_dst[node];
    int cnt = dg < CAPD ? dg : CAPD;
    const int* lst = adj_dst + (size_t)node * CAPD;
    float4 s = make_float4(0.f, 0.f, 0.f, 0.f);
    int e = 0;
    for (; e + 4 <= cnt; e += 4) {
        int i0 = lst[e], i1 = lst[e + 1], i2 = lst[e + 2], i3 = lst[e + 3];
        float4 a = h2[(size_t)i0 * 10 + l];
        float4 b = h2[(size_t)i1 * 10 + l];
        float4 c = h2[(size_t)i2 * 10 + l];
        float4 d = h2[(size_t)i3 * 10 + l];
        s.x += (a.x + b.x) + (c.x + d.x);
        s.y += (a.y + b.y) + (c.y + d.y);
        s.z += (a.z + b.z) + (c.z + d.z);
        s.w += (a.w + b.w) + (c.w + d.w);
    }
    for (; e < cnt; e++) {
        float4 a = h2[(size_t)lst[e] * 10 + l];
        s.x += a.x; s.y += a.y; s.z += a.z; s.w += a.w;
    }
    float nrm = rsqrtf((float)(dg > 1 ? dg : 1));
    float4 bb = b2[l];
    float4 v;
    v.x = s.x * nrm + bb.x;
    v.y = s.y * nrm + bb.y;
    v.z = s.z * nrm + bb.z;
    v.w = s.w * nrm + bb.w;
    out_x[(size_t)node * 10 + l] = v;
}

// ---------------------------------------------------------------------------
// LPA. y_t[u] = S_const[u] + sum_{unmasked nbr v} y_{t-1}[v]; y_1 == S_const,
// so lpa_const once then 9 steps. Masked rows of out_y = labels (final).
__global__ void lpa_init(const float* __restrict__ labels, const void* mask,
                         const int* __restrict__ flag, float* __restrict__ out_y) {
    int g = blockIdx.x * blockDim.x + threadIdx.x;
    if (g >= Nn * NC) return;
    int node = g / NC;
    if (read_mask(mask, node, *flag)) out_y[g] = labels[g];
}

__global__ __launch_bounds__(320) void lpa_const(
    const float4* __restrict__ labels, const int* __restrict__ n_un,
    const int* __restrict__ ulist, const int* __restrict__ adj_s,
    const int* __restrict__ cnt_m, float4* __restrict__ sconst) {
    int g = blockIdx.x * 32 + threadIdx.x / 10;
    int l = threadIdx.x % 10;
    if (g >= *n_un) return;
    int u = ulist[g];
    int cm = cnt_m[u];
    int cnt = cm < CAPS ? cm : CAPS;
    const int* lst = adj_s + (size_t)u * CAPS + (CAPS - cnt);
    float4 s = make_float4(0.f, 0.f, 0.f, 0.f);
    int e = 0;
    for (; e + 4 <= cnt; e += 4) {
        int i0 = lst[e], i1 = lst[e + 1], i2 = lst[e + 2], i3 = lst[e + 3];
        float4 a = labels[(size_t)i0 * 10 + l];
        float4 b = labels[(size_t)i1 * 10 + l];
        float4 c = labels[(size_t)i2 * 10 + l];
        float4 d = labels[(size_t)i3 * 10 + l];
        s.x += (a.x + b.x) + (c.x + d.x);
        s.y += (a.y + b.y) + (c.y + d.y);
        s.z += (a.z + b.z) + (c.z + d.z);
        s.w += (a.w + b.w) + (c.w + d.w);
    }
    for (; e < cnt; e++) {
        float4 a = labels[(size_t)lst[e] * 10 + l];
        s.x += a.x; s.y += a.y; s.z += a.z; s.w += a.w;
    }
    sconst[(size_t)u * 10 + l] = s;
}

__global__ __launch_bounds__(320) void lpa_step(
    const float4* __restrict__ ycur, const int* __restrict__ n_un,
    const int* __restrict__ ulist, const int* __restrict__ adj_s,
    const int* __restrict__ cnt_u, const float4* __restrict__ sconst,
    float4* __restrict__ ynext) {
    int g = blockIdx.x * 32 + threadIdx.x / 10;
    int l = threadIdx.x % 10;
    if (g >= *n_un) return;
    int u = ulist[g];
    int cu = cnt_u[u];
    int cnt = cu < CAPS ? cu : CAPS;
    const int* lst = adj_s + (size_t)u * CAPS;
    float4 s = sconst[(size_t)u * 10 + l];
    int e = 0;
    for (; e + 4 <= cnt; e += 4) {
        int i0 = lst[e], i1 = lst[e + 1], i2 = lst[e + 2], i3 = lst[e + 3];
        float4 a = ycur[(size_t)i0 * 10 + l];
        float4 b = ycur[(size_t)i1 * 10 + l];
        float4 c = ycur[(size_t)i2 * 10 + l];
        float4 d = ycur[(size_t)i3 * 10 + l];
        s.x += (a.x + b.x) + (c.x + d.x);
        s.y += (a.y + b.y) + (c.y + d.y);
        s.z += (a.z + b.z) + (c.z + d.z);
        s.w += (a.w + b.w) + (c.w + d.w);
    }
    for (; e < cnt; e++) {
        float4 a = ycur[(size_t)lst[e] * 10 + l];
        s.x += a.x; s.y += a.y; s.z += a.z; s.w += a.w;
    }
    ynext[(size_t)u * 10 + l] = s;
}

// ---------------------------------------------------------------------------
extern "C" void kernel_launch(void* const* d_in, const int* in_sizes, int n_in,
                              void* d_out, int out_size, void* d_ws, size_t ws_size,
                              hipStream_t stream) {
    const float* feat   = (const float*)d_in[0];
    const float* labels = (const float*)d_in[1];
    const void*  mask   = d_in[2];
    const int*   src    = (const int*)d_in[3];
    const int*   dst    = (const int*)d_in[4];
    const float* W1     = (const float*)d_in[5];
    const float* b1     = (const float*)d_in[6];
    const float* W2     = (const float*)d_in[7];
    const float* b2     = (const float*)d_in[8];

    float* out_x = (float*)d_out;
    float* out_y = out_x + (size_t)Nn * NC;

    char* ws = (char*)d_ws;
    size_t off = 0;
    auto alloc = [&](size_t bytes) -> void* {
        void* p = ws + off;
        off += (bytes + 255) & ~(size_t)255;
        return p;
    };
    // --- zeroed header: flag, cnt_src, cursors ---
    int* flag    = (int*)alloc(256);   // flag[0]=fmt, flag[1]=n_un
    int* n_un    = flag + 1;
    int* cnt_src = (int*)alloc((size_t)Nn * 4);
    int* cur_d   = (int*)alloc(512);
    int* cur_s   = (int*)alloc(512);
    size_t zero_bytes = off;
    // --- non-zeroed ---
    int* cnt_dst = (int*)alloc((size_t)Nn * 4);
    int* cnt_u   = (int*)alloc((size_t)Nn * 4);
    int* cnt_m   = (int*)alloc((size_t)Nn * 4);
    int* ulist   = (int*)alloc((size_t)Nn * 4);
    // --- big buffers; bucket bins alias h1 (dead before gemm1 writes) ---
    char* uni = (char*)alloc((size_t)Nn * HID * 4);        // 25.6MB union
    unsigned* bkt_d = (unsigned*)uni;                       // 98*10240*4 ~ 4.0MB
    unsigned* bkt_s = (unsigned*)(uni + (size_t)NB * CAPB_D * 4); // ~2.4MB
    float* h1 = (float*)uni;
    float* x1 = (float*)alloc((size_t)Nn * HID * 4);
    int* adj_s   = (int*)alloc((size_t)Nn * CAPS * 4);
    int* adj_dst = (int*)alloc((size_t)Nn * CAPD * 4);
    float* h2     = (float*)alloc((size_t)Nn * NC * 4);
    float* sconst = (float*)alloc((size_t)Nn * NC * 4);
    float* yA     = (float*)alloc((size_t)Nn * NC * 4);

    hipMemsetAsync(d_ws, 0, zero_bytes, stream);

    detect_fmt<<<49, 256, 0, stream>>>((const unsigned int*)mask, flag);
    bin_edges<<<NBLK, 256, 0, stream>>>(src, dst, mask, flag, cnt_src,
                                        cur_d, cur_s, bkt_d, bkt_s);
    build_csr_dst<<<NB, 256, 0, stream>>>(bkt_d, cur_d, adj_dst, cnt_dst);
    build_csr_src<<<NB, 256, 0, stream>>>(bkt_s, cur_s, mask, flag,
                                          adj_s, cnt_u, cnt_m);
    build_unmasked<<<196, 256, 0, stream>>>(mask, flag, n_un, ulist);

    gemm1<<<(Nn + G1_ROWS - 1) / G1_ROWS, 256, 0, stream>>>(feat, W1, cnt_src, h1);
    agg_relu1<<<Nn / 8, 256, 0, stream>>>((const float4*)h1, adj_dst, cnt_dst,
                                          (const float4*)b1, (float4*)x1);
    gemm2<<<(Nn + 31) / 32, 320, 0, stream>>>(x1, W2, cnt_src, h2);
    agg2<<<(Nn + 31) / 32, 320, 0, stream>>>((const float4*)h2, adj_dst, cnt_dst,
                                             (const float4*)b2, (float4*)out_x);

    lpa_init<<<(Nn * NC + 255) / 256, 256, 0, stream>>>(labels, mask, flag, out_y);
    lpa_const<<<(Nn + 31) / 32, 320, 0, stream>>>(
        (const float4*)labels, n_un, ulist, adj_s, cnt_m, (float4*)sconst);
    const float* cur = sconst;
    for (int t = 1; t <= LPA_ITERS - 1; t++) {
        float* nxt = (t & 1) ? out_y : yA;   // t=9 (last) -> out_y
        lpa_step<<<(Nn + 31) / 32, 320, 0, stream>>>(
            (const float4*)cur, n_un, ulist, adj_s, cnt_u,
            (const float4*)sconst, (float4*)nxt);
        cur = nxt;
    }
}

// Round 6
// 461.981 us; speedup vs baseline: 2.3350x; 1.0483x over previous
//
#include <hip/hip_runtime.h>

#define Nn 50000
#define Ee 800000
#define INF_ 256
#define HID 128
#define NC 40
#define CAPD 48      // adj_dst row capacity (Poisson(16) tail @48 ~1e-11)
#define CAPS 48      // adj_s row capacity (u-list front, m-list back)
#define LPA_ITERS 10
#define NB 98        // node buckets of 512
#define BSH 9
#define EPB 2048     // edges per bin_edges block
#define NBLK ((Ee + EPB - 1) / EPB)   // 391
#define CAPB_D 10240 // per-bucket bin capacity, dst direction (mean 8163)
#define CAPB_S 6144  // per-bucket bin capacity, src/unmasked (mean ~4081)

// ---------------------------------------------------------------------------
__global__ void detect_fmt(const unsigned int* __restrict__ m, int* flag) {
    int i = blockIdx.x * blockDim.x + threadIdx.x;
    if (i < 12500) {
        if (m[i] > 1u) atomicOr(flag, 1);
    }
}

__device__ inline bool read_mask(const void* mask, int node, int fmt) {
    if (fmt) return ((const unsigned char*)mask)[node] != 0;
    return ((const int*)mask)[node] != 0;
}

// ---------------------------------------------------------------------------
// Single-pass edge binning, both directions, one edge read. Fixed-capacity
// global bins (no prepass); LDS staging -> coalesced writebacks.
__global__ __launch_bounds__(256) void bin_edges(
    const int* __restrict__ src, const int* __restrict__ dst,
    const void* __restrict__ mask, const int* __restrict__ flag,
    int* __restrict__ cnt_src,
    int* __restrict__ cur_d, int* __restrict__ cur_s,
    unsigned* __restrict__ bkt_d, unsigned* __restrict__ bkt_s) {
    __shared__ unsigned stage_d[EPB];
    __shared__ unsigned stage_s[EPB];
    __shared__ int hd[NB], od[NB + 1], cd[NB], gd_[NB];
    __shared__ int hs[NB], os_[NB + 1], cs_[NB], gs_[NB];
    int tid = threadIdx.x;
    int e0 = blockIdx.x * EPB;
    int fmt = *flag;
    if (tid < NB) { hd[tid] = 0; hs[tid] = 0; }
    __syncthreads();

    int rs[EPB / 256], rd[EPB / 256];
    unsigned um = 0;  // bit k: src unmasked
#pragma unroll
    for (int k = 0; k < EPB / 256; k++) {
        int e = e0 + tid + k * 256;
        rs[k] = -1; rd[k] = -1;
        if (e < Ee) {
            int s = src[e], d = dst[e];
            rs[k] = s; rd[k] = d;
            atomicAdd(&cnt_src[s], 1);
            atomicAdd(&hd[d >> BSH], 1);
            if (!read_mask(mask, s, fmt)) {
                um |= (1u << k);
                atomicAdd(&hs[s >> BSH], 1);
            }
        }
    }
    __syncthreads();
    if (tid == 0) {
        int run = 0;
        for (int b = 0; b < NB; b++) { od[b] = run; run += hd[b]; }
        od[NB] = run;
        run = 0;
        for (int b = 0; b < NB; b++) { os_[b] = run; run += hs[b]; }
        os_[NB] = run;
    }
    __syncthreads();
    if (tid < NB) {
        gd_[tid] = hd[tid] ? atomicAdd(&cur_d[tid], hd[tid]) : 0;
        gs_[tid] = hs[tid] ? atomicAdd(&cur_s[tid], hs[tid]) : 0;
        cd[tid] = od[tid];
        cs_[tid] = os_[tid];
    }
    __syncthreads();
#pragma unroll
    for (int k = 0; k < EPB / 256; k++) {
        if (rd[k] >= 0) {
            int p = atomicAdd(&cd[rd[k] >> BSH], 1);
            stage_d[p] = ((unsigned)rd[k] << 16) | (unsigned)rs[k];
            if (um & (1u << k)) {
                int q = atomicAdd(&cs_[rs[k] >> BSH], 1);
                stage_s[q] = ((unsigned)rs[k] << 16) | (unsigned)rd[k];
            }
        }
    }
    __syncthreads();
    int totd = od[NB];
    for (int i = tid; i < totd; i += 256) {
        int lo = 0, hi = NB;
        while (hi - lo > 1) {
            int mid = (lo + hi) >> 1;
            if (od[mid] <= i) lo = mid; else hi = mid;
        }
        int pos = gd_[lo] + (i - od[lo]);
        if (pos < CAPB_D) bkt_d[(size_t)lo * CAPB_D + pos] = stage_d[i];
    }
    int tots = os_[NB];
    for (int i = tid; i < tots; i += 256) {
        int lo = 0, hi = NB;
        while (hi - lo > 1) {
            int mid = (lo + hi) >> 1;
            if (os_[mid] <= i) lo = mid; else hi = mid;
        }
        int pos = gs_[lo] + (i - os_[lo]);
        if (pos < CAPB_S) bkt_s[(size_t)lo * CAPB_S + pos] = stage_s[i];
    }
}

// Phase B (dst)
__global__ __launch_bounds__(256) void build_csr_dst(
    const unsigned* __restrict__ bkt, const int* __restrict__ cur,
    int* __restrict__ adj, int* __restrict__ cnt) {
    __shared__ int lc[512];
    int b = blockIdx.x, tid = threadIdx.x;
    lc[tid] = 0; lc[tid + 256] = 0;
    __syncthreads();
    int n = cur[b]; if (n > CAPB_D) n = CAPB_D;
    int n0 = b << BSH;
    const unsigned* base = bkt + (size_t)b * CAPB_D;
    for (int i = tid; i < n; i += 256) {
        unsigned r = base[i];
        int d = r >> 16, s = r & 0xffff;
        int sl = atomicAdd(&lc[d - n0], 1);
        if (sl < CAPD) adj[d * CAPD + sl] = s;
    }
    __syncthreads();
    int g0 = n0 + tid;
    if (g0 < Nn) cnt[g0] = lc[tid];
    g0 += 256;
    if (g0 < Nn) cnt[g0] = lc[tid + 256];
}

// Phase B (src): unmasked dst -> row front, masked dst -> row back.
__global__ __launch_bounds__(256) void build_csr_src(
    const unsigned* __restrict__ bkt, const int* __restrict__ cur,
    const void* __restrict__ mask, const int* __restrict__ flag,
    int* __restrict__ adj, int* __restrict__ cnt_u, int* __restrict__ cnt_m) {
    __shared__ int lu[512], lm[512];
    int b = blockIdx.x, tid = threadIdx.x;
    lu[tid] = 0; lu[tid + 256] = 0; lm[tid] = 0; lm[tid + 256] = 0;
    __syncthreads();
    int fmt = *flag;
    int n = cur[b]; if (n > CAPB_S) n = CAPB_S;
    int n0 = b << BSH;
    const unsigned* base = bkt + (size_t)b * CAPB_S;
    for (int i = tid; i < n; i += 256) {
        unsigned r = base[i];
        int s = r >> 16, d = r & 0xffff;
        if (read_mask(mask, d, fmt)) {
            int sl = atomicAdd(&lm[s - n0], 1);
            if (sl < CAPS) adj[s * CAPS + (CAPS - 1 - sl)] = d;
        } else {
            int sl = atomicAdd(&lu[s - n0], 1);
            if (sl < CAPS) adj[s * CAPS + sl] = d;
        }
    }
    __syncthreads();
    int g0 = n0 + tid;
    if (g0 < Nn) { cnt_u[g0] = lu[tid]; cnt_m[g0] = lm[tid]; }
    g0 += 256;
    if (g0 < Nn) { cnt_u[g0] = lu[tid + 256]; cnt_m[g0] = lm[tid + 256]; }
}

__global__ void build_unmasked(const void* __restrict__ mask,
                               const int* __restrict__ flag,
                               int* n_un, int* __restrict__ ulist) {
    int i = blockIdx.x * blockDim.x + threadIdx.x;
    if (i < Nn) {
        if (!read_mask(mask, i, *flag)) {
            int p = atomicAdd(n_un, 1);
            ulist[p] = i;
        }
    }
}

// ---------------------------------------------------------------------------
// GEMM1: h1[n, j] = (sum_k feat[n,k] * W1[k,j]) * norm_src[n]
// 64x128 block tile, thread tile 8 rows x 4 cols (c0=(tid&31)*4 -> one wave's
// B-read spans 512B = 2-way LDS aliasing = free; A-reads are broadcasts).
#define G1_ROWS 64
#define G1_KT 32
__global__ __launch_bounds__(256) void gemm1(
    const float* __restrict__ feat, const float* __restrict__ W1,
    const int* __restrict__ cnt_src, float* __restrict__ h1) {
    __shared__ float lA[G1_ROWS][G1_KT + 1];   // [row][k], +1 pad
    __shared__ float lB[G1_KT][HID];           // [k][col]
    const int tid = threadIdx.x;
    const int row0 = blockIdx.x * G1_ROWS;
    const int r0 = (tid >> 5) * 8;   // 8 rows/thread
    const int c0 = (tid & 31) * 4;   // 4 cols/thread

    float4 acc[8];
#pragma unroll
    for (int i = 0; i < 8; i++) acc[i] = make_float4(0.f, 0.f, 0.f, 0.f);

    for (int k0 = 0; k0 < INF_; k0 += G1_KT) {
        // stage A: 64 rows x 32 k = 512 float4, 2/thread
#pragma unroll
        for (int p = 0; p < 2; p++) {
            int idx = tid + p * 256;
            int r = idx >> 3, c4 = idx & 7;
            int grow = row0 + r;
            float4 v = make_float4(0.f, 0.f, 0.f, 0.f);
            if (grow < Nn)
                v = *(const float4*)(feat + (size_t)grow * INF_ + k0 + c4 * 4);
            lA[r][c4 * 4 + 0] = v.x;
            lA[r][c4 * 4 + 1] = v.y;
            lA[r][c4 * 4 + 2] = v.z;
            lA[r][c4 * 4 + 3] = v.w;
        }
        // stage B: 32 k x 128 cols = 1024 float4, 4/thread
#pragma unroll
        for (int p = 0; p < 4; p++) {
            int idx = tid + p * 256;
            int kb = idx >> 5, c4 = idx & 31;
            *(float4*)(&lB[kb][c4 * 4]) =
                *(const float4*)(W1 + (size_t)(k0 + kb) * HID + c4 * 4);
        }
        __syncthreads();
#pragma unroll 4
        for (int k = 0; k < G1_KT; k++) {
            float4 bv = *(const float4*)(&lB[k][c0]);
#pragma unroll
            for (int i = 0; i < 8; i++) {
                float a = lA[r0 + i][k];
                acc[i].x += a * bv.x;
                acc[i].y += a * bv.y;
                acc[i].z += a * bv.z;
                acc[i].w += a * bv.w;
            }
        }
        __syncthreads();
    }
#pragma unroll
    for (int i = 0; i < 8; i++) {
        int grow = row0 + r0 + i;
        if (grow < Nn) {
            int dg = cnt_src[grow];
            float nrm = rsqrtf((float)(dg > 1 ? dg : 1));
            float4 v;
            v.x = acc[i].x * nrm; v.y = acc[i].y * nrm;
            v.z = acc[i].z * nrm; v.w = acc[i].w * nrm;
            *(float4*)(h1 + (size_t)grow * HID + c0) = v;
        }
    }
}

// ---------------------------------------------------------------------------
// agg1: x1[i,:] = relu( norm_dst[i] * sum_{e: dst=i} h1[src_e,:] + b1 )
__global__ __launch_bounds__(256) void agg_relu1(
    const float4* __restrict__ h1, const int* __restrict__ adj_dst,
    const int* __restrict__ cnt_dst, const float4* __restrict__ b1,
    float4* __restrict__ x1) {
    int node = blockIdx.x * 8 + (threadIdx.x >> 5);
    int l = threadIdx.x & 31;
    int dg = cnt_dst[node];
    int cnt = dg < CAPD ? dg : CAPD;
    const int* lst = adj_dst + (size_t)node * CAPD;
    float4 s = make_float4(0.f, 0.f, 0.f, 0.f);
    int e = 0;
    for (; e + 8 <= cnt; e += 8) {
        float4 v[8];
#pragma unroll
        for (int q = 0; q < 8; q++) v[q] = h1[(size_t)lst[e + q] * 32 + l];
#pragma unroll
        for (int q = 0; q < 8; q++) {
            s.x += v[q].x; s.y += v[q].y; s.z += v[q].z; s.w += v[q].w;
        }
    }
    for (; e < cnt; e++) {
        float4 a = h1[(size_t)lst[e] * 32 + l];
        s.x += a.x; s.y += a.y; s.z += a.z; s.w += a.w;
    }
    float nrm = rsqrtf((float)(dg > 1 ? dg : 1));
    float4 bb = b1[l];
    float4 v;
    v.x = fmaxf(s.x * nrm + bb.x, 0.f);
    v.y = fmaxf(s.y * nrm + bb.y, 0.f);
    v.z = fmaxf(s.z * nrm + bb.z, 0.f);
    v.w = fmaxf(s.w * nrm + bb.w, 0.f);
    x1[(size_t)node * 32 + l] = v;
}

// ---------------------------------------------------------------------------
// GEMM2: h2[n,c] = (sum_k x1[n,k] * W2[k,c]) * norm_src[n]
// W2 (20KB) fully in LDS; one thread = one row, 40 f32 accumulators,
// all LDS reads are whole-wave broadcasts (conflict-free).
__global__ __launch_bounds__(256) void gemm2(
    const float4* __restrict__ x1, const float4* __restrict__ W2,
    const int* __restrict__ cnt_src, float* __restrict__ h2) {
    __shared__ float lw[HID * NC];   // 5120 floats = 20KB
    int tid = threadIdx.x;
    for (int i = tid; i < HID * NC / 4; i += 256)
        ((float4*)lw)[i] = W2[i];
    __syncthreads();
    int r = blockIdx.x * 256 + tid;
    if (r >= Nn) return;
    const float4* xr = x1 + (size_t)r * 32;
    float4 acc[10];
#pragma unroll
    for (int j = 0; j < 10; j++) acc[j] = make_float4(0.f, 0.f, 0.f, 0.f);
    for (int k4 = 0; k4 < 32; k4++) {
        float4 xv = xr[k4];
#pragma unroll
        for (int s = 0; s < 4; s++) {
            float x = s == 0 ? xv.x : (s == 1 ? xv.y : (s == 2 ? xv.z : xv.w));
            const float4* wrow = (const float4*)(lw + (k4 * 4 + s) * NC);
#pragma unroll
            for (int j = 0; j < 10; j++) {
                float4 w = wrow[j];
                acc[j].x += x * w.x; acc[j].y += x * w.y;
                acc[j].z += x * w.z; acc[j].w += x * w.w;
            }
        }
    }
    int dg = cnt_src[r];
    float nrm = rsqrtf((float)(dg > 1 ? dg : 1));
    float4* out = (float4*)(h2 + (size_t)r * NC);
#pragma unroll
    for (int j = 0; j < 10; j++) {
        float4 v;
        v.x = acc[j].x * nrm; v.y = acc[j].y * nrm;
        v.z = acc[j].z * nrm; v.w = acc[j].w * nrm;
        out[j] = v;
    }
}

// ---------------------------------------------------------------------------
// agg2: out_x[i,c] = norm_dst[i] * sum_{e: dst=i} h2[src_e,c] + b2[c]
__global__ __launch_bounds__(320) void agg2(
    const float4* __restrict__ h2, const int* __restrict__ adj_dst,
    const int* __restrict__ cnt_dst, const float4* __restrict__ b2,
    float4* __restrict__ out_x) {
    int node = blockIdx.x * 32 + threadIdx.x / 10;
    int l = threadIdx.x % 10;
    if (node >= Nn) return;
    int dg = cnt_dst[node];
    int cnt = dg < CAPD ? dg : CAPD;
    const int* lst = adj_dst + (size_t)node * CAPD;
    float4 s = make_float4(0.f, 0.f, 0.f, 0.f);
    int e = 0;
    for (; e + 8 <= cnt; e += 8) {
        float4 v[8];
#pragma unroll
        for (int q = 0; q < 8; q++) v[q] = h2[(size_t)lst[e + q] * 10 + l];
#pragma unroll
        for (int q = 0; q < 8; q++) {
            s.x += v[q].x; s.y += v[q].y; s.z += v[q].z; s.w += v[q].w;
        }
    }
    for (; e + 4 <= cnt; e += 4) {
        float4 v[4];
#pragma unroll
        for (int q = 0; q < 4; q++) v[q] = h2[(size_t)lst[e + q] * 10 + l];
#pragma unroll
        for (int q = 0; q < 4; q++) {
            s.x += v[q].x; s.y += v[q].y; s.z += v[q].z; s.w += v[q].w;
        }
    }
    for (; e < cnt; e++) {
        float4 a = h2[(size_t)lst[e] * 10 + l];
        s.x += a.x; s.y += a.y; s.z += a.z; s.w += a.w;
    }
    float nrm = rsqrtf((float)(dg > 1 ? dg : 1));
    float4 bb = b2[l];
    float4 v;
    v.x = s.x * nrm + bb.x;
    v.y = s.y * nrm + bb.y;
    v.z = s.z * nrm + bb.z;
    v.w = s.w * nrm + bb.w;
    out_x[(size_t)node * 10 + l] = v;
}

// ---------------------------------------------------------------------------
// LPA
__global__ void lpa_init(const float* __restrict__ labels, const void* mask,
                         const int* __restrict__ flag, float* __restrict__ out_y) {
    int g = blockIdx.x * blockDim.x + threadIdx.x;
    if (g >= Nn * NC) return;
    int node = g / NC;
    if (read_mask(mask, node, *flag)) out_y[g] = labels[g];
}

__global__ __launch_bounds__(320) void lpa_const(
    const float4* __restrict__ labels, const int* __restrict__ n_un,
    const int* __restrict__ ulist, const int* __restrict__ adj_s,
    const int* __restrict__ cnt_m, float4* __restrict__ sconst) {
    int g = blockIdx.x * 32 + threadIdx.x / 10;
    int l = threadIdx.x % 10;
    if (g >= *n_un) return;
    int u = ulist[g];
    int cm = cnt_m[u];
    int cnt = cm < CAPS ? cm : CAPS;
    const int* lst = adj_s + (size_t)u * CAPS + (CAPS - cnt);
    float4 s = make_float4(0.f, 0.f, 0.f, 0.f);
    int e = 0;
    for (; e + 8 <= cnt; e += 8) {
        float4 v[8];
#pragma unroll
        for (int q = 0; q < 8; q++) v[q] = labels[(size_t)lst[e + q] * 10 + l];
#pragma unroll
        for (int q = 0; q < 8; q++) {
            s.x += v[q].x; s.y += v[q].y; s.z += v[q].z; s.w += v[q].w;
        }
    }
    for (; e + 4 <= cnt; e += 4) {
        float4 v[4];
#pragma unroll
        for (int q = 0; q < 4; q++) v[q] = labels[(size_t)lst[e + q] * 10 + l];
#pragma unroll
        for (int q = 0; q < 4; q++) {
            s.x += v[q].x; s.y += v[q].y; s.z += v[q].z; s.w += v[q].w;
        }
    }
    for (; e < cnt; e++) {
        float4 a = labels[(size_t)lst[e] * 10 + l];
        s.x += a.x; s.y += a.y; s.z += a.z; s.w += a.w;
    }
    sconst[(size_t)u * 10 + l] = s;
}

__global__ __launch_bounds__(320) void lpa_step(
    const float4* __restrict__ ycur, const int* __restrict__ n_un,
    const int* __restrict__ ulist, const int* __restrict__ adj_s,
    const int* __restrict__ cnt_u, const float4* __restrict__ sconst,
    float4* __restrict__ ynext) {
    int g = blockIdx.x * 32 + threadIdx.x / 10;
    int l = threadIdx.x % 10;
    if (g >= *n_un) return;
    int u = ulist[g];
    int cu = cnt_u[u];
    int cnt = cu < CAPS ? cu : CAPS;
    const int* lst = adj_s + (size_t)u * CAPS;
    float4 s = sconst[(size_t)u * 10 + l];
    int e = 0;
    for (; e + 8 <= cnt; e += 8) {
        float4 v[8];
#pragma unroll
        for (int q = 0; q < 8; q++) v[q] = ycur[(size_t)lst[e + q] * 10 + l];
#pragma unroll
        for (int q = 0; q < 8; q++) {
            s.x += v[q].x; s.y += v[q].y; s.z += v[q].z; s.w += v[q].w;
        }
    }
    for (; e + 4 <= cnt; e += 4) {
        float4 v[4];
#pragma unroll
        for (int q = 0; q < 4; q++) v[q] = ycur[(size_t)lst[e + q] * 10 + l];
#pragma unroll
        for (int q = 0; q < 4; q++) {
            s.x += v[q].x; s.y += v[q].y; s.z += v[q].z; s.w += v[q].w;
        }
    }
    for (; e < cnt; e++) {
        float4 a = ycur[(size_t)lst[e] * 10 + l];
        s.x += a.x; s.y += a.y; s.z += a.z; s.w += a.w;
    }
    ynext[(size_t)u * 10 + l] = s;
}

// ---------------------------------------------------------------------------
extern "C" void kernel_launch(void* const* d_in, const int* in_sizes, int n_in,
                              void* d_out, int out_size, void* d_ws, size_t ws_size,
                              hipStream_t stream) {
    const float* feat   = (const float*)d_in[0];
    const float* labels = (const float*)d_in[1];
    const void*  mask   = d_in[2];
    const int*   src    = (const int*)d_in[3];
    const int*   dst    = (const int*)d_in[4];
    const float* W1     = (const float*)d_in[5];
    const float* b1     = (const float*)d_in[6];
    const float* W2     = (const float*)d_in[7];
    const float* b2     = (const float*)d_in[8];

    float* out_x = (float*)d_out;
    float* out_y = out_x + (size_t)Nn * NC;

    char* ws = (char*)d_ws;
    size_t off = 0;
    auto alloc = [&](size_t bytes) -> void* {
        void* p = ws + off;
        off += (bytes + 255) & ~(size_t)255;
        return p;
    };
    // --- zeroed header ---
    int* flag    = (int*)alloc(256);   // flag[0]=fmt, flag[1]=n_un
    int* n_un    = flag + 1;
    int* cnt_src = (int*)alloc((size_t)Nn * 4);
    int* cur_d   = (int*)alloc(512);
    int* cur_s   = (int*)alloc(512);
    size_t zero_bytes = off;
    // --- non-zeroed ---
    int* cnt_dst = (int*)alloc((size_t)Nn * 4);
    int* cnt_u   = (int*)alloc((size_t)Nn * 4);
    int* cnt_m   = (int*)alloc((size_t)Nn * 4);
    int* ulist   = (int*)alloc((size_t)Nn * 4);
    // --- big buffers; bucket bins alias h1 (dead before gemm1 writes) ---
    char* uni = (char*)alloc((size_t)Nn * HID * 4);        // 25.6MB union
    unsigned* bkt_d = (unsigned*)uni;                       // ~4.0MB
    unsigned* bkt_s = (unsigned*)(uni + (size_t)NB * CAPB_D * 4); // ~2.4MB
    float* h1 = (float*)uni;
    float* x1 = (float*)alloc((size_t)Nn * HID * 4);
    int* adj_s   = (int*)alloc((size_t)Nn * CAPS * 4);
    int* adj_dst = (int*)alloc((size_t)Nn * CAPD * 4);
    float* h2     = (float*)alloc((size_t)Nn * NC * 4);
    float* sconst = (float*)alloc((size_t)Nn * NC * 4);
    float* yA     = (float*)alloc((size_t)Nn * NC * 4);

    hipMemsetAsync(d_ws, 0, zero_bytes, stream);

    detect_fmt<<<49, 256, 0, stream>>>((const unsigned int*)mask, flag);
    bin_edges<<<NBLK, 256, 0, stream>>>(src, dst, mask, flag, cnt_src,
                                        cur_d, cur_s, bkt_d, bkt_s);
    build_csr_dst<<<NB, 256, 0, stream>>>(bkt_d, cur_d, adj_dst, cnt_dst);
    build_csr_src<<<NB, 256, 0, stream>>>(bkt_s, cur_s, mask, flag,
                                          adj_s, cnt_u, cnt_m);
    build_unmasked<<<196, 256, 0, stream>>>(mask, flag, n_un, ulist);

    gemm1<<<(Nn + G1_ROWS - 1) / G1_ROWS, 256, 0, stream>>>(feat, W1, cnt_src, h1);
    agg_relu1<<<Nn / 8, 256, 0, stream>>>((const float4*)h1, adj_dst, cnt_dst,
                                          (const float4*)b1, (float4*)x1);
    gemm2<<<196, 256, 0, stream>>>((const float4*)x1, (const float4*)W2,
                                   cnt_src, h2);
    agg2<<<(Nn + 31) / 32, 320, 0, stream>>>((const float4*)h2, adj_dst, cnt_dst,
                                             (const float4*)b2, (float4*)out_x);

    lpa_init<<<(Nn * NC + 255) / 256, 256, 0, stream>>>(labels, mask, flag, out_y);
    lpa_const<<<(Nn + 31) / 32, 320, 0, stream>>>(
        (const float4*)labels, n_un, ulist, adj_s, cnt_m, (float4*)sconst);
    const float* cur = sconst;
    for (int t = 1; t <= LPA_ITERS - 1; t++) {
        float* nxt = (t & 1) ? out_y : yA;   // t=9 (last) -> out_y
        lpa_step<<<(Nn + 31) / 32, 320, 0, stream>>>(
            (const float4*)cur, n_un, ulist, adj_s, cnt_u,
            (const float4*)sconst, (float4*)nxt);
        cur = nxt;
    }
}